// Round 8
// baseline (1142.344 us; speedup 1.0000x reference)
//
#include <hip/hip_runtime.h>
#include <math.h>

// ---------------------------------------------------------------------------
// WaveletNet forward. MFMA implicit GEMM convs (f16), heavy launch fusion:
// wavelet/GN/concat transforms write padded NHWC f16 conv inputs directly.
// N=16 fixed.
// ---------------------------------------------------------------------------

#define NB 16  // batch

typedef _Float16 f16;
typedef _Float16 f16x8 __attribute__((ext_vector_type(8)));
typedef _Float16 f16x4 __attribute__((ext_vector_type(4)));
typedef float f32x4 __attribute__((ext_vector_type(4)));
typedef unsigned int u32;

#define LLDS16(gp, lp)                                                          \
  __builtin_amdgcn_global_load_lds((const __attribute__((address_space(1))) u32*)(const void*)(gp), \
                                   (__attribute__((address_space(3))) u32*)(void*)(lp), 16, 0, 0)

// ---------------- weight standardization (shared body) ----------------
__device__ __forceinline__ void ws_reduce(const float* wp, int fan, float* red,
                                          float& mean, float& inv) {
  float s = 0.f, s2 = 0.f;
  for (int i = threadIdx.x; i < fan; i += 256) { float v = wp[i]; s += v; s2 += v * v; }
  red[threadIdx.x] = s; red[256 + threadIdx.x] = s2;
  __syncthreads();
  for (int st = 128; st > 0; st >>= 1) {
    if (threadIdx.x < st) {
      red[threadIdx.x] += red[threadIdx.x + st];
      red[256 + threadIdx.x] += red[256 + threadIdx.x + st];
    }
    __syncthreads();
  }
  float sum = red[0], sumsq = red[256];
  mean = sum / (float)fan;
  float var = (sumsq - sum * mean) / (float)(fan - 1);
  if (var < 0.f) var = 0.f;
  inv = 1.0f / (sqrtf(var) + 1e-5f);
}

// all fp32 ws in one ladder kernel (grid = 46)
__global__ void ws_all_kernel(const float* w0, float* o0, const float* w1, float* o1,
                              const float* w2, float* o2, const float* w3, float* o3) {
  __shared__ float red[512];
  int b = blockIdx.x;
  const float* w; float* o; int fan, oi;
  if (b < 16)      { w = w0; o = o0; fan = 108; oi = b; }
  else if (b < 28) { w = w1; o = o1; fan = 144; oi = b - 16; }
  else if (b < 44) { w = w2; o = o2; fan = 288; oi = b - 28; }
  else             { w = w3; o = o3; fan = 3;   oi = b - 44; }
  const float* wp = w + (size_t)oi * fan;
  float mean, inv; ws_reduce(wp, fan, red, mean, inv);
  for (int i = threadIdx.x; i < fan; i += 256)
    o[(size_t)oi * fan + i] = (wp[i] - mean) * inv;
}

// all f16 packed ws in one ladder kernel (grid = 1664); pack [tap][Cout][Cin]
__global__ void ws_f16_all_kernel(const float* w0, f16* o0, const float* w1, f16* o1,
                                  const float* w2, f16* o2, const float* w3, f16* o3,
                                  const float* w4, f16* o4) {
  __shared__ float red[512];
  int b = blockIdx.x;
  const float* w; f16* o; int fan, Cin, Cout, oi;
  if (b < 64)        { w = w0; o = o0; fan = 576;  Cin = 64;   Cout = 64;   oi = b; }
  else if (b < 320)  { w = w1; o = o1; fan = 2304; Cin = 256;  Cout = 256;  oi = b - 64; }
  else if (b < 1344) { w = w2; o = o2; fan = 9216; Cin = 1024; Cout = 1024; oi = b - 320; }
  else if (b < 1408) { w = w3; o = o3; fan = 1152; Cin = 128;  Cout = 64;   oi = b - 1344; }
  else               { w = w4; o = o4; fan = 4608; Cin = 512;  Cout = 256;  oi = b - 1408; }
  const float* wp = w + (size_t)oi * fan;
  float mean, inv; ws_reduce(wp, fan, red, mean, inv);
  for (int i = threadIdx.x; i < fan; i += 256) {
    int ci = i / 9, tap = i - ci * 9;
    o[((size_t)tap * Cout + oi) * Cin + ci] = (f16)((wp[i] - mean) * inv);
  }
}

// ---------------- halo zero (shared body + 3-segment upfront kernel) --------
__device__ __forceinline__ void halo_write(f16* buf, int C, int H, int W, int t) {
  int c8s = C >> 3;
  int c8 = t % c8s; int q = t / c8s;
  int P = 2 * (W + 2) + 2 * H;
  int b = q % P; int n = q / P;
  int y, x;
  if (b < W + 2) { y = 0; x = b; }
  else if (b < 2 * (W + 2)) { y = H + 1; x = b - (W + 2); }
  else { int bb = b - 2 * (W + 2); y = 1 + (bb >> 1); x = (bb & 1) ? (W + 1) : 0; }
  size_t a = (((size_t)n * (H + 2) + y) * (W + 2) + x) * C + c8 * 8;
  *(f16x8*)(buf + a) = (f16x8){0, 0, 0, 0, 0, 0, 0, 0};
}

__global__ void halo3_kernel(f16* b0, int c0, int h0, int w0, int n0,
                             f16* b1, int c1, int h1, int w1, int n1,
                             f16* b2, int c2, int h2, int w2, int total) {
  int idx = blockIdx.x * 256 + threadIdx.x;
  if (idx >= total) return;
  if (idx < n0) halo_write(b0, c0, h0, w0, idx);
  else if (idx < n0 + n1) halo_write(b1, c1, h1, w1, idx - n0);
  else halo_write(b2, c2, h2, w2, idx - n0 - n1);
}

// ---------------- Haar forward (plain NCHW, for w1 only) ----------------
__global__ void wt_kernel(const float* __restrict__ in, float* __restrict__ out,
                          int C, int Ho, int Wo, int total) {
  int idx = blockIdx.x * 256 + threadIdx.x;
  if (idx >= total) return;
  int w = idx % Wo; int t = idx / Wo;
  int h = t % Ho; t /= Ho;
  int c = t % C; int n = t / C;
  int Wi = 2 * Wo;
  const float* ip = in + (((size_t)n * C + c) * (2 * Ho) + 2 * h) * Wi + 2 * w;
  float a = ip[0], b = ip[1], cc = ip[Wi], d = ip[Wi + 1];
  size_t cs = (size_t)Ho * Wo;
  float* op = out + (((size_t)n * 4 * C + 4 * c) * Ho + h) * Wo + w;
  op[0]      = 0.25f * (a + b + cc + d);
  op[cs]     = 0.25f * (a + b - cc - d) + 0.5f;
  op[2 * cs] = 0.25f * (a - b + cc - d) + 0.5f;
  op[3 * cs] = 0.25f * (a - b - cc + d) + 0.5f;
}

// ---------------- Haar forward -> padded NHWC f16 (+optional fp32 NCHW) -----
// in: (N,C,2Ho,2Wo) fp32. out: padded NHWC f16 with 4C channels at (Ho,Wo).
__global__ void wt_nhwc_kernel(const float* __restrict__ in, f16* __restrict__ out,
                               float* __restrict__ wout, int C, int Ho, int Wo, int total) {
  int idx = blockIdx.x * 256 + threadIdx.x;
  if (idx >= total) return;
  int C4 = 4 * C;
  int c8s = C4 >> 3;
  int c8 = idx % c8s; int t = idx / c8s;
  int x = t % Wo; t /= Wo;
  int y = t % Ho; int n = t / Ho;
  int oc0 = c8 * 8;
  int Wi = 2 * Wo;
  float vals[8];
#pragma unroll
  for (int s = 0; s < 2; ++s) {
    int c = (oc0 >> 2) + s;
    const float* ip = in + (((size_t)n * C + c) * (2 * Ho) + 2 * y) * Wi + 2 * x;
    float a = ip[0], b = ip[1], cc = ip[Wi], d = ip[Wi + 1];
    vals[s * 4 + 0] = 0.25f * (a + b + cc + d);
    vals[s * 4 + 1] = 0.25f * (a + b - cc - d) + 0.5f;
    vals[s * 4 + 2] = 0.25f * (a - b + cc - d) + 0.5f;
    vals[s * 4 + 3] = 0.25f * (a - b - cc + d) + 0.5f;
  }
  f16x8 h;
#pragma unroll
  for (int r = 0; r < 8; ++r) h[r] = (f16)vals[r];
  *(f16x8*)(out + (((size_t)n * (Ho + 2) + y + 1) * (Wo + 2) + x + 1) * C4 + oc0) = h;
  if (wout) {
#pragma unroll
    for (int r = 0; r < 8; ++r)
      wout[(((size_t)n * C4 + oc0 + r) * Ho + y) * Wo + x] = vals[r];
  }
}

// ---------------- GN-apply + NCHW->padded NHWC f16 ----------------
// grid: (HW/256, C/32, N); interior only (halo pre-zeroed).
__global__ __launch_bounds__(256) void gn_nhwc_kernel(
    const float* __restrict__ in, const float* __restrict__ stats,
    const float* __restrict__ gamma, const float* __restrict__ beta,
    f16* __restrict__ out, int C, int H, int W, int G) {
  __shared__ f16 sm[32][264];
  int HW = H * W;
  int p0 = blockIdx.x * 256, c0 = blockIdx.y * 32, n = blockIdx.z;
  int t = threadIdx.x;
  int cpg = C / G;
  const float* ip = in + ((size_t)n * C + c0) * HW + p0;
#pragma unroll 8
  for (int r = 0; r < 32; ++r) {
    int c = c0 + r; int g = c / cpg;
    float mean = stats[(n * G + g) * 2], inv = stats[(n * G + g) * 2 + 1];
    float ga = gamma[c], be = beta[c];
    sm[r][t] = (f16)((ip[(size_t)r * HW + t] - mean) * inv * ga + be);
  }
  __syncthreads();
#pragma unroll
  for (int i = 0; i < 4; ++i) {
    int c = t + i * 256;
    int pl = c >> 2, cio = (c & 3) * 8;
    f16x8 v;
#pragma unroll
    for (int u = 0; u < 8; ++u) v[u] = sm[cio + u][pl];
    int p = p0 + pl; int y = p / W; int x = p - y * W;
    *(f16x8*)(out + (((size_t)n * (H + 2) + y + 1) * (W + 2) + x + 1) * C + c0 + cio) = v;
  }
}

// ---------------- decoder concat prep -> padded NHWC f16 ----------------
// out 2C channels @ (H,W): [0,C) = skip (fp32 NCHW, already GN'd);
// [C,2C) = iwt of v (fp32 NCHW, 4C ch @ (H/2,W/2)), optional inline GN on v.
// Grid also covers halo blocks (total = interior + halo count).
__global__ void dec_nhwc_kernel(const float* __restrict__ skip, const float* __restrict__ v,
                                const float* __restrict__ stats, const float* __restrict__ gamma,
                                const float* __restrict__ beta, f16* __restrict__ out,
                                int C, int H, int W, int G, int total_int, int total) {
  int idx = blockIdx.x * 256 + threadIdx.x;
  if (idx >= total) return;
  int C2 = 2 * C;
  if (idx >= total_int) { halo_write(out, C2, H, W, idx - total_int); return; }
  int c8s = C2 >> 3;
  int c8 = idx % c8s; int t = idx / c8s;
  int x = t % W; t /= W;
  int y = t % H; int n = t / H;
  f16x8 h;
  if (c8 * 8 < C) {
    const float* sp = skip + ((size_t)n * C + c8 * 8) * H * W + (size_t)y * W + x;
    size_t HW = (size_t)H * W;
#pragma unroll
    for (int r = 0; r < 8; ++r) h[r] = (f16)sp[r * HW];
  } else {
    int oc0 = c8 * 8 - C;
    int hh = y >> 1, ww = x >> 1;
    int Hh = H >> 1, Wh = W >> 1;
    size_t cs = (size_t)Hh * Wh;
    float s1 = (y & 1) ? -0.5f : 0.5f;
    float s2 = (x & 1) ? -0.5f : 0.5f;
    float s3 = ((x ^ y) & 1) ? -0.5f : 0.5f;
    int Cv = 4 * C; int cpg = G > 0 ? Cv / G : 1;
#pragma unroll
    for (int r = 0; r < 8; ++r) {
      int c = oc0 + r;
      const float* vp = v + ((size_t)n * Cv + 4 * c) * cs + (size_t)hh * Wh + ww;
      float v0 = vp[0], v1 = vp[cs], v2 = vp[2 * cs], v3 = vp[3 * cs];
      if (stats) {
#pragma unroll
        for (int k = 0; k < 4; ++k) {
          int ch = 4 * c + k; int g = ch / cpg;
          float mean = stats[(n * G + g) * 2], inv = stats[(n * G + g) * 2 + 1];
          float val = k == 0 ? v0 : (k == 1 ? v1 : (k == 2 ? v2 : v3));
          val = (val - mean) * inv * gamma[ch] + beta[ch];
          if (k == 0) v0 = val; else if (k == 1) v1 = val; else if (k == 2) v2 = val; else v3 = val;
        }
      }
      v1 = 2.f * v1 - 1.f; v2 = 2.f * v2 - 1.f; v3 = 2.f * v3 - 1.f;
      h[r] = (f16)(v0 + s1 * v1 + s2 * v2 + s3 * v3);
    }
  }
  *(f16x8*)(out + (((size_t)n * (H + 2) + y + 1) * (W + 2) + x + 1) * C2 + c8 * 8) = h;
}

// ---------------- decoder stage-2 concat -> fp32 NCHW (32ch @128^2) ---------
// part A (idx < totalA): copy skip c1 (16@128^2) f32x4. part B: GN+iwt of v (64@64^2).
__global__ void dec_nchw_kernel(const float* __restrict__ skip, const float* __restrict__ v,
                                const float* __restrict__ stats, const float* __restrict__ gamma,
                                const float* __restrict__ beta, float* __restrict__ out,
                                int totalA, int total) {
  int idx = blockIdx.x * 256 + threadIdx.x;
  if (idx >= total) return;
  if (idx < totalA) {  // NB*16*128*32
    int x4 = idx % 32; int t = idx / 32;
    int hh = t % 128; t /= 128;
    int c = t % 16; int n = t / 16;
    f32x4 val = *(const f32x4*)(skip + (((size_t)n * 16 + c) * 128 + hh) * 128 + x4 * 4);
    *(f32x4*)(out + (((size_t)n * 32 + c) * 128 + hh) * 128 + x4 * 4) = val;
    return;
  }
  int i2 = idx - totalA;  // NB*16*64*64
  int w = i2 % 64; int t = i2 / 64;
  int h = t % 64; t /= 64;
  int c = t % 16; int n = t / 16;
  size_t cs = (size_t)64 * 64;
  const float* vp = v + ((size_t)n * 64 + 4 * c) * cs + (size_t)h * 64 + w;
  float vv[4];
#pragma unroll
  for (int k = 0; k < 4; ++k) {
    int ch = 4 * c + k; int g = ch / 8;  // gn2: C=64,G=8
    float mean = stats[(n * 8 + g) * 2], inv = stats[(n * 8 + g) * 2 + 1];
    vv[k] = (vp[k * cs] - mean) * inv * gamma[ch] + beta[ch];
  }
  float v0 = vv[0];
  float v1 = 2.f * vv[1] - 1.f, v2 = 2.f * vv[2] - 1.f, v3 = 2.f * vv[3] - 1.f;
  float* op = out + (((size_t)n * 32 + 16 + c) * 128 + 2 * h) * 128 + 2 * w;
  op[0]   = v0 + 0.5f * ( v1 + v2 + v3);
  op[1]   = v0 + 0.5f * ( v1 - v2 - v3);
  op[128] = v0 + 0.5f * (-v1 + v2 - v3);
  op[129] = v0 + 0.5f * (-v1 - v2 + v3);
}

// ---------------- fused final iwt + 1x1 ws-conv ----------------
// v: 12@128^2 fp32 -> iwt 3@256^2 -> out (N,2,256,256) with weights w[6].
__global__ void iwt_final_kernel(const float* __restrict__ v, const float* __restrict__ w,
                                 float* __restrict__ out, int total) {
  int idx = blockIdx.x * 256 + threadIdx.x;
  if (idx >= total) return;  // NB*128*128
  int ww = idx % 128; int t = idx / 128;
  int hh = t % 128; int n = t / 128;
  size_t cs = (size_t)128 * 128;
  float y0[3], y1[3], y2[3], y3[3];
#pragma unroll
  for (int c = 0; c < 3; ++c) {
    const float* vp = v + ((size_t)n * 12 + 4 * c) * cs + (size_t)hh * 128 + ww;
    float v0 = vp[0];
    float v1 = 2.f * vp[cs] - 1.f, v2 = 2.f * vp[2 * cs] - 1.f, v3 = 2.f * vp[3 * cs] - 1.f;
    y0[c] = v0 + 0.5f * ( v1 + v2 + v3);
    y1[c] = v0 + 0.5f * ( v1 - v2 - v3);
    y2[c] = v0 + 0.5f * (-v1 + v2 - v3);
    y3[c] = v0 + 0.5f * (-v1 - v2 + v3);
  }
  float w0 = w[0], w1 = w[1], w2 = w[2], w3 = w[3], w4 = w[4], w5 = w[5];
  size_t ocs = (size_t)256 * 256;
  float* o0 = out + (size_t)n * 2 * ocs + (size_t)(2 * hh) * 256 + 2 * ww;
  o0[0]   = w0 * y0[0] + w1 * y0[1] + w2 * y0[2];
  o0[1]   = w0 * y1[0] + w1 * y1[1] + w2 * y1[2];
  o0[256] = w0 * y2[0] + w1 * y2[1] + w2 * y2[2];
  o0[257] = w0 * y3[0] + w1 * y3[1] + w2 * y3[2];
  float* o1 = o0 + ocs;
  o1[0]   = w3 * y0[0] + w4 * y0[1] + w5 * y0[2];
  o1[1]   = w3 * y1[0] + w4 * y1[1] + w5 * y1[2];
  o1[256] = w3 * y2[0] + w4 * y2[1] + w5 * y2[2];
  o1[257] = w3 * y3[0] + w4 * y3[1] + w5 * y3[2];
}

// ---------------- conv_mfma5: 128x128x64, split-K = gridDim.z ----------------
__global__ __launch_bounds__(256) void conv_mfma5_kernel(
    const f16* __restrict__ A, const f16* __restrict__ Wp,
    f16* __restrict__ part, int Cin, int H, int W, int Cout, int HW) {
  constexpr int BM = 128, BN = 128, BK = 64;
  __shared__ f16 Asm[BM * BK];
  __shared__ f16 Bsm[BN * BK];

  const int tid = threadIdx.x;
  const int w = tid >> 6, lane = tid & 63;
  const int m0 = blockIdx.x * BM;
  const int co0 = blockIdx.y * BN;
  const int Wp2 = W + 2;

  const f16* gA[4]; const f16* gB[4];
  int lOff[4];
#pragma unroll
  for (int e = 0; e < 4; ++e) {
    int c = e * 256 + tid;
    int r = c >> 3, j = c & 7;
    int jx = j ^ (r & 7);
    int m = m0 + r; int n = m / HW; int p = m - n * HW;
    int y = p / W; int x = p - y * W;
    gA[e] = A + (((size_t)n * (H + 2) + y + 1) * Wp2 + (x + 1)) * Cin + jx * 8;
    gB[e] = Wp + (size_t)(co0 + r) * Cin + jx * 8;
    lOff[e] = (e * 256 + w * 64) * 8;
  }

  const int wm = w & 1, wn = w >> 1;
  const int lr = lane & 15, quad = lane >> 4;
  int aoffs[4][2], boffs[4][2];
#pragma unroll
  for (int i = 0; i < 4; ++i)
#pragma unroll
    for (int kk = 0; kk < 2; ++kk) {
      int r = wm * 64 + i * 16 + lr;
      int cidx = kk * 4 + quad;
      aoffs[i][kk] = (r * 8 + (cidx ^ (r & 7))) * 8;
      int rb = wn * 64 + i * 16 + lr;
      boffs[i][kk] = (rb * 8 + (cidx ^ (rb & 7))) * 8;
    }

  f32x4 acc[4][4];
#pragma unroll
  for (int i = 0; i < 4; ++i)
#pragma unroll
    for (int j = 0; j < 4; ++j) acc[i][j] = (f32x4){0.f, 0.f, 0.f, 0.f};

  const int kpt = Cin >> 6;
  const int nit = (9 * kpt) / gridDim.z;
  const size_t bstride = (size_t)Cout * Cin;

  int it0 = blockIdx.z * nit;
  int tap = it0 / kpt, kc = (it0 - tap * kpt) << 6;

  for (int ii = 0; ii < nit; ++ii) {
    int dy = tap / 3 - 1, dx = tap % 3 - 1;
    long offA = ((long)dy * Wp2 + dx) * Cin + kc;
    long offB = (long)tap * bstride + kc;
    __syncthreads();
#pragma unroll
    for (int e = 0; e < 4; ++e) {
      LLDS16(gA[e] + offA, Asm + lOff[e]);
      LLDS16(gB[e] + offB, Bsm + lOff[e]);
    }
    __syncthreads();

    f16x8 af[4][2], bf[4][2];
#pragma unroll
    for (int i = 0; i < 4; ++i)
#pragma unroll
      for (int kk = 0; kk < 2; ++kk) {
        af[i][kk] = *(const f16x8*)&Asm[aoffs[i][kk]];
        bf[i][kk] = *(const f16x8*)&Bsm[boffs[i][kk]];
      }
#pragma unroll
    for (int kk = 0; kk < 2; ++kk)
#pragma unroll
      for (int i = 0; i < 4; ++i)
#pragma unroll
        for (int j = 0; j < 4; ++j)
          acc[i][j] = __builtin_amdgcn_mfma_f32_16x16x32_f16(af[i][kk], bf[j][kk], acc[i][j], 0, 0, 0);

    kc += 64;
    if (kc == Cin) { kc = 0; ++tap; }
  }

  const size_t pbase = (size_t)blockIdx.z * NB * Cout * HW;
#pragma unroll
  for (int i = 0; i < 4; ++i) {
    int mg = m0 + wm * 64 + i * 16 + quad * 4;
    int n = mg / HW, p = mg - n * HW;
#pragma unroll
    for (int j = 0; j < 4; ++j) {
      int co = co0 + wn * 64 + j * 16 + lr;
      f32x4 v = acc[i][j];
      f16x4 h;
#pragma unroll
      for (int r = 0; r < 4; ++r) h[r] = (f16)v[r];
      *(f16x4*)&part[pbase + ((size_t)n * Cout + co) * HW + p] = h;
    }
  }
}

// ---------------- reduce S partials + bias (+add) (+lrelu) -> fp32 ----------
__global__ __launch_bounds__(256) void reduceS_kernel(
    const f16* __restrict__ part, const float* __restrict__ bias,
    const float* __restrict__ add, float* __restrict__ out,
    int Cout, int HW, int S, int do_lrelu, int total4) {
  int idx = blockIdx.x * 256 + threadIdx.x;
  if (idx >= total4) return;
  size_t sstride = (size_t)NB * Cout * HW;
  int hw4 = HW >> 2;
  int p4 = idx % hw4; int t = idx / hw4;
  int c = t % Cout;
  size_t eoff = (size_t)t * HW + p4 * 4;
  float b = bias[c];
  f32x4 o = {b, b, b, b};
  for (int s = 0; s < S; ++s) {
    f16x4 a = *(const f16x4*)(part + s * sstride + eoff);
#pragma unroll
    for (int r = 0; r < 4; ++r) o[r] += (float)a[r];
  }
  if (add) {
    f32x4 av = *(const f32x4*)(add + eoff);
#pragma unroll
    for (int r = 0; r < 4; ++r) o[r] += av[r];
  }
  if (do_lrelu)
#pragma unroll
    for (int r = 0; r < 4; ++r) o[r] = o[r] > 0.f ? o[r] : 0.2f * o[r];
  *(f32x4*)(out + eoff) = o;
}

// ---------------- conv_mfma2: 128x64x64 single-buffer (Cout=64 shapes) ------
__global__ __launch_bounds__(256) void conv_mfma2_kernel(
    const f16* __restrict__ A, const f16* __restrict__ Wp,
    const float* __restrict__ bias, float* __restrict__ out,
    int Cin, int H, int W, int Cout, int HW, int do_lrelu) {
  constexpr int BM = 128, BN = 64, BK = 64;
  __shared__ f16 Asm[BM * BK];
  __shared__ f16 Bsm[BN * BK];

  const int tid = threadIdx.x;
  const int w = tid >> 6, lane = tid & 63;
  const int m0 = blockIdx.x * BM;
  const int co0 = blockIdx.y * BN;
  const int Wp2 = W + 2;

  const f16* gA[4];
  int lAoff[4];
#pragma unroll
  for (int e = 0; e < 4; ++e) {
    int c = e * 256 + tid;
    int r = c >> 3, j = c & 7;
    int jx = j ^ (r & 7);
    int m = m0 + r; int n = m / HW; int p = m - n * HW;
    int y = p / W; int x = p - y * W;
    gA[e] = A + (((size_t)n * (H + 2) + y + 1) * Wp2 + (x + 1)) * Cin + jx * 8;
    lAoff[e] = (e * 256 + w * 64) * 8;
  }
  const f16* gB[2];
  int lBoff[2];
#pragma unroll
  for (int e = 0; e < 2; ++e) {
    int c = e * 256 + tid;
    int r = c >> 3, j = c & 7;
    int jx = j ^ (r & 7);
    gB[e] = Wp + (size_t)(co0 + r) * Cin + jx * 8;
    lBoff[e] = (e * 256 + w * 64) * 8;
  }

  const int wm = w & 1, wn = w >> 1;
  const int lr = lane & 15, quad = lane >> 4;
  int aoffs[4][2], boffs[2][2];
#pragma unroll
  for (int i = 0; i < 4; ++i)
#pragma unroll
    for (int kk = 0; kk < 2; ++kk) {
      int r = wm * 64 + i * 16 + lr;
      int cidx = kk * 4 + quad;
      aoffs[i][kk] = (r * 8 + (cidx ^ (r & 7))) * 8;
    }
#pragma unroll
  for (int jn = 0; jn < 2; ++jn)
#pragma unroll
    for (int kk = 0; kk < 2; ++kk) {
      int rb = wn * 32 + jn * 16 + lr;
      int cidx = kk * 4 + quad;
      boffs[jn][kk] = (rb * 8 + (cidx ^ (rb & 7))) * 8;
    }

  f32x4 acc[4][2];
#pragma unroll
  for (int i = 0; i < 4; ++i)
#pragma unroll
    for (int jn = 0; jn < 2; ++jn) acc[i][jn] = (f32x4){0.f, 0.f, 0.f, 0.f};

  for (int tap = 0; tap < 9; ++tap) {
    const int dy = tap / 3 - 1, dx = tap % 3 - 1;
    const long tapA = ((long)dy * Wp2 + dx) * Cin;
    const long tapB = (size_t)tap * Cout * Cin;
    for (int kc = 0; kc < Cin; kc += BK) {
      __syncthreads();
#pragma unroll
      for (int e = 0; e < 4; ++e) LLDS16(gA[e] + tapA + kc, Asm + lAoff[e]);
#pragma unroll
      for (int e = 0; e < 2; ++e) LLDS16(gB[e] + tapB + kc, Bsm + lBoff[e]);
      __syncthreads();

      f16x8 af[4][2], bf[2][2];
#pragma unroll
      for (int i = 0; i < 4; ++i)
#pragma unroll
        for (int kk = 0; kk < 2; ++kk) af[i][kk] = *(const f16x8*)&Asm[aoffs[i][kk]];
#pragma unroll
      for (int jn = 0; jn < 2; ++jn)
#pragma unroll
        for (int kk = 0; kk < 2; ++kk) bf[jn][kk] = *(const f16x8*)&Bsm[boffs[jn][kk]];
#pragma unroll
      for (int kk = 0; kk < 2; ++kk)
#pragma unroll
        for (int i = 0; i < 4; ++i)
#pragma unroll
          for (int jn = 0; jn < 2; ++jn)
            acc[i][jn] = __builtin_amdgcn_mfma_f32_16x16x32_f16(af[i][kk], bf[jn][kk], acc[i][jn], 0, 0, 0);
    }
  }

#pragma unroll
  for (int i = 0; i < 4; ++i) {
    int mg = m0 + wm * 64 + i * 16 + quad * 4;
    int n = mg / HW, p = mg - n * HW;
#pragma unroll
    for (int jn = 0; jn < 2; ++jn) {
      int co = co0 + wn * 32 + jn * 16 + lr;
      float b = bias[co];
      f32x4 v = acc[i][jn];
#pragma unroll
      for (int r = 0; r < 4; ++r) {
        float u = v[r] + b;
        v[r] = (do_lrelu && u < 0.f) ? 0.2f * u : u;
      }
      *(f32x4*)&out[((size_t)n * Cout + co) * HW + p] = v;
    }
  }
}

// ---------------- direct 3x3 conv (small channel counts) ----------------
template <int CO, int CIC>
__global__ __launch_bounds__(256) void conv3x3_kernel(
    const float* __restrict__ in, const float* __restrict__ wgt,
    const float* __restrict__ bias, float* __restrict__ out,
    int Cin, int H, int W, int Cout, int do_lrelu) {
  __shared__ float sm[CIC][18][18];
  int tiles_x = W >> 4;
  int bt = blockIdx.x;
  int tx0 = (bt % tiles_x) << 4;
  int ty0 = (bt / tiles_x) << 4;
  int co0 = blockIdx.y * CO;
  int n = blockIdx.z;
  int tid = threadIdx.x;
  int lx = tid & 15, ly = tid >> 4;

  float acc[CO];
#pragma unroll
  for (int i = 0; i < CO; i++) acc[i] = 0.f;

  const float* inb = in + (size_t)n * Cin * H * W;

  for (int ci0 = 0; ci0 < Cin; ci0 += CIC) {
    __syncthreads();
    for (int idx = tid; idx < CIC * 324; idx += 256) {
      int ci = idx / 324;
      int r = idx - ci * 324;
      int gy = r / 18, gx = r - gy * 18;
      int iy = ty0 + gy - 1, ix = tx0 + gx - 1;
      float v = 0.f;
      if ((unsigned)iy < (unsigned)H && (unsigned)ix < (unsigned)W)
        v = inb[((size_t)(ci0 + ci)) * H * W + (size_t)iy * W + ix];
      sm[ci][gy][gx] = v;
    }
    __syncthreads();
#pragma unroll
    for (int ci = 0; ci < CIC; ci++) {
      float x00 = sm[ci][ly][lx],     x01 = sm[ci][ly][lx + 1],     x02 = sm[ci][ly][lx + 2];
      float x10 = sm[ci][ly + 1][lx], x11 = sm[ci][ly + 1][lx + 1], x12 = sm[ci][ly + 1][lx + 2];
      float x20 = sm[ci][ly + 2][lx], x21 = sm[ci][ly + 2][lx + 1], x22 = sm[ci][ly + 2][lx + 2];
      const float* wp = wgt + ((size_t)co0 * Cin + (ci0 + ci)) * 9;
#pragma unroll
      for (int co = 0; co < CO; co++) {
        const float* wc = wp + (size_t)co * Cin * 9;
        float a = acc[co];
        a = fmaf(wc[0], x00, a); a = fmaf(wc[1], x01, a); a = fmaf(wc[2], x02, a);
        a = fmaf(wc[3], x10, a); a = fmaf(wc[4], x11, a); a = fmaf(wc[5], x12, a);
        a = fmaf(wc[6], x20, a); a = fmaf(wc[7], x21, a); a = fmaf(wc[8], x22, a);
        acc[co] = a;
      }
    }
  }

  int oy = ty0 + ly, ox = tx0 + lx;
#pragma unroll
  for (int co = 0; co < CO; co++) {
    float v = acc[co] + bias[co0 + co];
    if (do_lrelu) v = v > 0.f ? v : 0.2f * v;
    out[(((size_t)n * Cout + co0 + co) * H + oy) * W + ox] = v;
  }
}

// ---------------- group norm: stats / combine / apply ----------------
__global__ __launch_bounds__(256) void gn_stats_kernel(const float* __restrict__ x,
                                                       float* __restrict__ part,
                                                       int C, int HW, int G, int SPLIT) {
  __shared__ float red[512];
  int gs = blockIdx.x;
  int g = gs / SPLIT, s = gs - g * SPLIT;
  int n = blockIdx.y;
  int cpg = C / G;
  int len = cpg * HW;
  int chunk = len / SPLIT;
  size_t base = ((size_t)n * C + (size_t)g * cpg) * HW + (size_t)s * chunk;
  const f32x4* xp = (const f32x4*)(x + base);
  int chunk4 = chunk >> 2;
  float sm = 0.f, s2 = 0.f;
  for (int i = threadIdx.x; i < chunk4; i += 256) {
    f32x4 v = xp[i];
    sm += v.x + v.y + v.z + v.w;
    s2 += v.x * v.x + v.y * v.y + v.z * v.z + v.w * v.w;
  }
  red[threadIdx.x] = sm; red[256 + threadIdx.x] = s2;
  __syncthreads();
  for (int st = 128; st > 0; st >>= 1) {
    if (threadIdx.x < st) {
      red[threadIdx.x] += red[threadIdx.x + st];
      red[256 + threadIdx.x] += red[256 + threadIdx.x + st];
    }
    __syncthreads();
  }
  if (threadIdx.x == 0) {
    int o = ((n * G + g) * SPLIT + s) * 2;
    part[o] = red[0]; part[o + 1] = red[256];
  }
}

__global__ void gn_combine_kernel(const float* __restrict__ part, float* __restrict__ stats,
                                  int SPLIT, int len, int total) {
  int idx = blockIdx.x * 256 + threadIdx.x;
  if (idx >= total) return;
  float s = 0.f, s2 = 0.f;
  for (int i = 0; i < SPLIT; ++i) { s += part[(idx * SPLIT + i) * 2]; s2 += part[(idx * SPLIT + i) * 2 + 1]; }
  float mean = s / (float)len;
  float var = s2 / (float)len - mean * mean;
  if (var < 0.f) var = 0.f;
  stats[idx * 2] = mean;
  stats[idx * 2 + 1] = rsqrtf(var + 1e-5f);
}

__global__ __launch_bounds__(256) void gn_apply_kernel(float* __restrict__ x,
                                                       const float* __restrict__ stats,
                                                       const float* __restrict__ gamma,
                                                       const float* __restrict__ beta,
                                                       int C, int HW, int G, int total4) {
  int idx = blockIdx.x * 256 + threadIdx.x;
  if (idx >= total4) return;
  int hw4 = HW >> 2;
  int p4 = idx % hw4; int t = idx / hw4;
  int c = t % C; int n = t / C;
  int cpg = C / G; int g = c / cpg;
  float mean = stats[(n * G + g) * 2];
  float inv  = stats[(n * G + g) * 2 + 1];
  float ga = gamma[c], be = beta[c];
  f32x4* xp = (f32x4*)(x + ((size_t)t * HW)) + p4;
  f32x4 v = *xp;
#pragma unroll
  for (int r = 0; r < 4; ++r) v[r] = (v[r] - mean) * inv * ga + be;
  *xp = v;
}

// ---------------------------------------------------------------------------

extern "C" void kernel_launch(void* const* d_in, const int* in_sizes, int n_in,
                              void* d_out, int out_size, void* d_ws, size_t ws_size,
                              hipStream_t stream) {
  const float* x        = (const float*)d_in[0];
  const float* conv1_w  = (const float*)d_in[1];
  const float* conv1_b  = (const float*)d_in[2];
  const float* conv2_w  = (const float*)d_in[3];
  const float* conv2_b  = (const float*)d_in[4];
  const float* conv3_w  = (const float*)d_in[5];
  const float* conv3_b  = (const float*)d_in[6];
  const float* conv4_w  = (const float*)d_in[7];
  const float* conv4_b  = (const float*)d_in[8];
  const float* convd1_w = (const float*)d_in[9];
  const float* convd1_b = (const float*)d_in[10];
  const float* convd2_w = (const float*)d_in[11];
  const float* convd2_b = (const float*)d_in[12];
  const float* convd3_w = (const float*)d_in[13];
  const float* convd3_b = (const float*)d_in[14];
  const float* convd4_w = (const float*)d_in[15];
  const float* convd4_b = (const float*)d_in[16];
  const float* final_w  = (const float*)d_in[17];
  const float* gn1_w = (const float*)d_in[18];
  const float* gn1_b = (const float*)d_in[19];
  const float* gn2_w = (const float*)d_in[20];
  const float* gn2_b = (const float*)d_in[21];
  const float* gn3_w = (const float*)d_in[22];
  const float* gn3_b = (const float*)d_in[23];
  const float* gn4_w = (const float*)d_in[24];
  const float* gn4_b = (const float*)d_in[25];

  char* base = (char*)d_ws;
  size_t off = 0;
  auto allocB = [&](size_t bytes) { size_t o = off; off = (off + bytes + 255) & ~(size_t)255; return o; };

  size_t o_sw1  = allocB(16 * 108 * 4);
  size_t o_swd1 = allocB(12 * 144 * 4);
  size_t o_swd2 = allocB(16 * 288 * 4);
  size_t o_swf  = allocB(6 * 4);
  size_t o_pw2  = allocB((size_t)9 * 64 * 64 * 2);
  size_t o_pw3  = allocB((size_t)9 * 256 * 256 * 2);
  size_t o_pw4  = allocB((size_t)9 * 1024 * 1024 * 2);
  size_t o_pwd3 = allocB((size_t)9 * 64 * 128 * 2);
  size_t o_pwd4 = allocB((size_t)9 * 256 * 512 * 2);
  // region R1: part (4 splits, 33.6 MB) aliased with ah64 / ah128 (disjoint lifetimes)
  size_t o_R1   = allocB((size_t)4 * NB * 1024 * 256 * 2);
  // region R2: ah256 aliased with ah512
  size_t o_R2   = allocB((size_t)NB * 34 * 34 * 512 * 2);
  size_t o_ah1k = allocB((size_t)NB * 18 * 18 * 1024 * 2);
  size_t o_gnp  = allocB(4096 * 4);
  size_t o_gns  = allocB(4096 * 4);
  size_t o_c1 = allocB((size_t)NB * 16 * 128 * 128 * 4);
  size_t o_c2 = allocB((size_t)NB * 64 * 64 * 64 * 4);
  size_t o_c3 = allocB((size_t)NB * 256 * 32 * 32 * 4);
  size_t o_w4 = allocB((size_t)NB * 1024 * 16 * 16 * 4);
  size_t o_t1 = allocB((size_t)NB * 1024 * 16 * 16 * 4);
  size_t o_t2 = allocB((size_t)NB * 512 * 32 * 32 * 4);

  if (off > ws_size) return;

  float* c1 = (float*)(base + o_c1);
  float* c2 = (float*)(base + o_c2);
  float* c3 = (float*)(base + o_c3);
  float* w4 = (float*)(base + o_w4);
  float* t1 = (float*)(base + o_t1);
  float* t2 = (float*)(base + o_t2);
  f16* part  = (f16*)(base + o_R1);
  f16* ah64  = (f16*)(base + o_R1);   // lifetime [wt2, conv2] — before part's first use
  f16* ah128 = (f16*)(base + o_R1);   // lifetime [dec3, convd3] — after part's last use
  f16* ah256 = (f16*)(base + o_R2);   // [wt3, conv3]
  f16* ah512 = (f16*)(base + o_R2);   // [dec4, icd4]
  f16* ah1k  = (f16*)(base + o_ah1k);
  f16* pw2 = (f16*)(base + o_pw2);
  f16* pw3 = (f16*)(base + o_pw3);
  f16* pw4 = (f16*)(base + o_pw4);
  f16* pwd3 = (f16*)(base + o_pwd3);
  f16* pwd4 = (f16*)(base + o_pwd4);
  float* gnp = (float*)(base + o_gnp);
  float* gns = (float*)(base + o_gns);

  // ---- upfront halo zero: ah64, ah256, ah1k (aliased ah128/ah512 get in-kernel halo) ----
  {
    int n0 = NB * (2 * 66 + 2 * 64) * (64 / 8);      // ah64
    int n1 = NB * (2 * 34 + 2 * 32) * (256 / 8);     // ah256
    int n2 = NB * (2 * 18 + 2 * 16) * (1024 / 8);    // ah1k
    int tot = n0 + n1 + n2;
    halo3_kernel<<<(tot + 255) / 256, 256, 0, stream>>>(
        ah64, 64, 64, 64, n0, ah256, 256, 32, 32, n1, ah1k, 1024, 16, 16, tot);
  }
  // ---- weight prep (2 launches) ----
  ws_all_kernel<<<46, 256, 0, stream>>>(conv1_w, (float*)(base + o_sw1),
                                        convd1_w, (float*)(base + o_swd1),
                                        convd2_w, (float*)(base + o_swd2),
                                        final_w, (float*)(base + o_swf));
  ws_f16_all_kernel<<<1664, 256, 0, stream>>>(conv2_w, pw2, conv3_w, pw3, conv4_w, pw4,
                                              convd3_w, pwd3, convd4_w, pwd4);

  auto gn_sc = [&](const float* xb, int C, int HW, int G) {  // stats + combine only
    int SPLIT = 2048 / (G * NB);
    if (SPLIT < 1) SPLIT = 1;
    int len = (C / G) * HW;
    dim3 gsd(G * SPLIT, NB);
    gn_stats_kernel<<<gsd, 256, 0, stream>>>(xb, gnp, C, HW, G, SPLIT);
    int tot = NB * G;
    gn_combine_kernel<<<(tot + 255) / 256, 256, 0, stream>>>(gnp, gns, SPLIT, len, tot);
  };
  auto gn_full = [&](float* xb, const float* g, const float* b, int C, int HW, int G) {
    gn_sc(xb, C, HW, G);
    int total4 = (NB * C * HW) >> 2;
    gn_apply_kernel<<<(total4 + 255) / 256, 256, 0, stream>>>(xb, gns, g, b, C, HW, G, total4);
  };
  auto cm5 = [&](const f16* a, const f16* wt, const float* b, float* dest, const float* add,
                 int Cin, int Hs, int Ws, int Cout, int S, int lr) {
    dim3 g((NB * Hs * Ws) / 128, Cout / 128, S);
    conv_mfma5_kernel<<<g, 256, 0, stream>>>(a, wt, part, Cin, Hs, Ws, Cout, Hs * Ws);
    int total4 = (NB * Cout * Hs * Ws) >> 2;
    reduceS_kernel<<<(total4 + 255) / 256, 256, 0, stream>>>(part, b, add, dest,
                                                             Cout, Hs * Ws, S, lr, total4);
  };
  auto cm2 = [&](const f16* a, const f16* wt, const float* b, float* o,
                 int Cin, int Hs, int Ws, int Cout, int lr) {
    dim3 g((NB * Hs * Ws) / 128, Cout / 64);
    conv_mfma2_kernel<<<g, 256, 0, stream>>>(a, wt, b, o, Cin, Hs, Ws, Cout, Hs * Ws, lr);
  };

  // ==== encoder ====
  {  // w1 = wt(x) -> t1 (16,12,128,128)
    int total = NB * 3 * 128 * 128;
    wt_kernel<<<(total + 255) / 256, 256, 0, stream>>>(x, t1, 3, 128, 128, total);
  }
  {  // c1 = lrelu(conv1(w1))
    dim3 g(64, 2, NB);
    conv3x3_kernel<8, 4><<<g, 256, 0, stream>>>(t1, (float*)(base + o_sw1), conv1_b,
                                                c1, 12, 128, 128, 16, 1);
  }
  gn_full(c1, gn1_w, gn1_b, 16, 128 * 128, 2);

  {  // w2 = wt(c1) -> ah64 (NHWC f16, 64ch@64x64)
    int total = NB * 64 * 64 * (64 / 8);
    wt_nhwc_kernel<<<(total + 255) / 256, 256, 0, stream>>>(c1, ah64, nullptr, 16, 64, 64, total);
  }
  cm2(ah64, pw2, conv2_b, c2, 64, 64, 64, 64, 1);             // c2
  gn_full(c2, gn2_w, gn2_b, 64, 64 * 64, 8);

  {  // w3 = wt(c2) -> ah256
    int total = NB * 32 * 32 * (256 / 8);
    wt_nhwc_kernel<<<(total + 255) / 256, 256, 0, stream>>>(c2, ah256, nullptr, 64, 32, 32, total);
  }
  cm5(ah256, pw3, conv3_b, c3, nullptr, 256, 32, 32, 256, 2, 1);   // c3
  gn_full(c3, gn3_w, gn3_b, 256, 32 * 32, 32);

  {  // w4 = wt(c3) -> ah1k + fp32 copy in w4
    int total = NB * 16 * 16 * (1024 / 8);
    wt_nhwc_kernel<<<(total + 255) / 256, 256, 0, stream>>>(c3, ah1k, w4, 256, 16, 16, total);
  }

  cm5(ah1k, pw4, conv4_b, t1, nullptr, 1024, 16, 16, 1024, 4, 1);  // c4 -> t1
  gn_sc(t1, 1024, 256, 128);
  {
    dim3 g(1, 32, NB);
    gn_nhwc_kernel<<<g, 256, 0, stream>>>(t1, gns, gn4_w, gn4_b, ah1k, 1024, 16, 16, 128);
  }
  cm5(ah1k, pw4, conv4_b, t2, nullptr, 1024, 16, 16, 1024, 4, 1);  // c5 -> t2
  gn_sc(t2, 1024, 256, 128);
  {
    dim3 g(1, 32, NB);
    gn_nhwc_kernel<<<g, 256, 0, stream>>>(t2, gns, gn4_w, gn4_b, ah1k, 1024, 16, 16, 128);
  }
  cm5(ah1k, pw4, conv4_b, t1, w4, 1024, 16, 16, 1024, 4, 1);       // ic4 = lrelu(c6+w4) -> t1

  // ==== decoder ====
  {  // iw4 = [c3, iwt(ic4)] -> ah512 (512ch@32x32), no GN on ic4; in-kernel halo
    int ti = NB * 32 * 32 * (512 / 8);
    int th = NB * (2 * 34 + 2 * 32) * (512 / 8);
    int tot = ti + th;
    dec_nhwc_kernel<<<(tot + 255) / 256, 256, 0, stream>>>(
        c3, t1, nullptr, nullptr, nullptr, ah512, 256, 32, 32, 0, ti, tot);
  }
  cm5(ah512, pwd4, convd4_b, t1, nullptr, 512, 32, 32, 256, 2, 1); // ic3(pre-GN) -> t1
  gn_sc(t1, 256, 1024, 32);
  {  // iw3 = [c2, iwt(gn3(ic3))] -> ah128 (128ch@64x64); in-kernel halo
    int ti = NB * 64 * 64 * (128 / 8);
    int th = NB * (2 * 66 + 2 * 64) * (128 / 8);
    int tot = ti + th;
    dec_nhwc_kernel<<<(tot + 255) / 256, 256, 0, stream>>>(
        c2, t1, gns, gn3_w, gn3_b, ah128, 64, 64, 64, 32, ti, tot);
  }
  cm2(ah128, pwd3, convd3_b, t1, 128, 64, 64, 64, 1);              // ic2(pre-GN) -> t1
  gn_sc(t1, 64, 4096, 8);
  {  // iw2 = [c1, iwt(gn2(ic2))] -> t2 fp32 NCHW (32@128^2)
    int totalA = NB * 16 * 128 * 32;
    int total = totalA + NB * 16 * 64 * 64;
    dec_nchw_kernel<<<(total + 255) / 256, 256, 0, stream>>>(
        c1, t1, gns, gn2_w, gn2_b, t2, totalA, total);
  }
  {  // ic1 = lrelu(convd2(iw2)) -> t1
    dim3 g(64, 2, NB);
    conv3x3_kernel<8, 4><<<g, 256, 0, stream>>>(t2, (float*)(base + o_swd2), convd2_b,
                                                t1, 32, 128, 128, 16, 1);
  }
  gn_full(t1, gn1_w, gn1_b, 16, 128 * 128, 2);
  {  // iw1 = lrelu(convd1(ic1)) -> t2 (12@128^2)
    dim3 g(64, 3, NB);
    conv3x3_kernel<4, 4><<<g, 256, 0, stream>>>(t1, (float*)(base + o_swd1), convd1_b,
                                                t2, 16, 128, 128, 12, 1);
  }
  {  // y = final_conv(iwt(iw1)) -> d_out
    int total = NB * 128 * 128;
    iwt_final_kernel<<<(total + 255) / 256, 256, 0, stream>>>(t2, (float*)(base + o_swf),
                                                              (float*)d_out, total);
  }
}

// Round 9
// 1024.895 us; speedup vs baseline: 1.1146x; 1.1146x over previous
//
#include <hip/hip_runtime.h>
#include <math.h>

// ---------------------------------------------------------------------------
// WaveletNet forward. R7 coalesced graph + ws/gn/iwt fusions + CO=16 direct
// convs. MFMA implicit GEMM (f16): conv_mfma5 128x128x64 split-K=2 for
// Cout>=128, conv_mfma2 128x64x64 for Cout=64. N=16 fixed.
// ---------------------------------------------------------------------------

#define NB 16  // batch

typedef _Float16 f16;
typedef _Float16 f16x8 __attribute__((ext_vector_type(8)));
typedef _Float16 f16x4 __attribute__((ext_vector_type(4)));
typedef float f32x4 __attribute__((ext_vector_type(4)));
typedef unsigned int u32;

#define LLDS16(gp, lp)                                                          \
  __builtin_amdgcn_global_load_lds((const __attribute__((address_space(1))) u32*)(const void*)(gp), \
                                   (__attribute__((address_space(3))) u32*)(void*)(lp), 16, 0, 0)

// ---------------- weight standardization (shared body) ----------------
__device__ __forceinline__ void ws_reduce(const float* wp, int fan, float* red,
                                          float& mean, float& inv) {
  float s = 0.f, s2 = 0.f;
  for (int i = threadIdx.x; i < fan; i += 256) { float v = wp[i]; s += v; s2 += v * v; }
  red[threadIdx.x] = s; red[256 + threadIdx.x] = s2;
  __syncthreads();
  for (int st = 128; st > 0; st >>= 1) {
    if (threadIdx.x < st) {
      red[threadIdx.x] += red[threadIdx.x + st];
      red[256 + threadIdx.x] += red[256 + threadIdx.x + st];
    }
    __syncthreads();
  }
  float sum = red[0], sumsq = red[256];
  mean = sum / (float)fan;
  float var = (sumsq - sum * mean) / (float)(fan - 1);
  if (var < 0.f) var = 0.f;
  inv = 1.0f / (sqrtf(var) + 1e-5f);
}

__global__ void ws_all_kernel(const float* w0, float* o0, const float* w1, float* o1,
                              const float* w2, float* o2, const float* w3, float* o3) {
  __shared__ float red[512];
  int b = blockIdx.x;
  const float* w; float* o; int fan, oi;
  if (b < 16)      { w = w0; o = o0; fan = 108; oi = b; }
  else if (b < 28) { w = w1; o = o1; fan = 144; oi = b - 16; }
  else if (b < 44) { w = w2; o = o2; fan = 288; oi = b - 28; }
  else             { w = w3; o = o3; fan = 3;   oi = b - 44; }
  const float* wp = w + (size_t)oi * fan;
  float mean, inv; ws_reduce(wp, fan, red, mean, inv);
  for (int i = threadIdx.x; i < fan; i += 256)
    o[(size_t)oi * fan + i] = (wp[i] - mean) * inv;
}

// pack [tap][Cout][Cin] f16
__global__ void ws_f16_all_kernel(const float* w0, f16* o0, const float* w1, f16* o1,
                                  const float* w2, f16* o2, const float* w3, f16* o3,
                                  const float* w4, f16* o4) {
  __shared__ float red[512];
  int b = blockIdx.x;
  const float* w; f16* o; int fan, Cin, Cout, oi;
  if (b < 64)        { w = w0; o = o0; fan = 576;  Cin = 64;   Cout = 64;   oi = b; }
  else if (b < 320)  { w = w1; o = o1; fan = 2304; Cin = 256;  Cout = 256;  oi = b - 64; }
  else if (b < 1344) { w = w2; o = o2; fan = 9216; Cin = 1024; Cout = 1024; oi = b - 320; }
  else if (b < 1408) { w = w3; o = o3; fan = 1152; Cin = 128;  Cout = 64;   oi = b - 1344; }
  else               { w = w4; o = o4; fan = 4608; Cin = 512;  Cout = 256;  oi = b - 1408; }
  const float* wp = w + (size_t)oi * fan;
  float mean, inv; ws_reduce(wp, fan, red, mean, inv);
  for (int i = threadIdx.x; i < fan; i += 256) {
    int ci = i / 9, tap = i - ci * 9;
    o[((size_t)tap * Cout + oi) * Cin + ci] = (f16)((wp[i] - mean) * inv);
  }
}

// ---------------- halo zero ----------------
__device__ __forceinline__ void halo_write(f16* buf, int C, int H, int W, int t) {
  int c8s = C >> 3;
  int c8 = t % c8s; int q = t / c8s;
  int P = 2 * (W + 2) + 2 * H;
  int b = q % P; int n = q / P;
  int y, x;
  if (b < W + 2) { y = 0; x = b; }
  else if (b < 2 * (W + 2)) { y = H + 1; x = b - (W + 2); }
  else { int bb = b - 2 * (W + 2); y = 1 + (bb >> 1); x = (bb & 1) ? (W + 1) : 0; }
  size_t a = (((size_t)n * (H + 2) + y) * (W + 2) + x) * C + c8 * 8;
  *(f16x8*)(buf + a) = (f16x8){0, 0, 0, 0, 0, 0, 0, 0};
}

__global__ void halo2_kernel(f16* b0, int c0, int h0, int w0, int n0,
                             f16* b1, int c1, int h1, int w1, int total) {
  int idx = blockIdx.x * 256 + threadIdx.x;
  if (idx >= total) return;
  if (idx < n0) halo_write(b0, c0, h0, w0, idx);
  else halo_write(b1, c1, h1, w1, idx - n0);
}

__global__ void zero_halo_kernel(f16* __restrict__ buf, int C, int H, int W, int total8) {
  int idx = blockIdx.x * 256 + threadIdx.x;
  if (idx >= total8) return;
  halo_write(buf, C, H, W, idx);
}

// ---------------- Haar forward (NCHW fp32) ----------------
__global__ void wt_kernel(const float* __restrict__ in, float* __restrict__ out,
                          int C, int Ho, int Wo, int total) {
  int idx = blockIdx.x * 256 + threadIdx.x;
  if (idx >= total) return;
  int w = idx % Wo; int t = idx / Wo;
  int h = t % Ho; t /= Ho;
  int c = t % C; int n = t / C;
  int Wi = 2 * Wo;
  const float* ip = in + (((size_t)n * C + c) * (2 * Ho) + 2 * h) * Wi + 2 * w;
  float a = ip[0], b = ip[1], cc = ip[Wi], d = ip[Wi + 1];
  size_t cs = (size_t)Ho * Wo;
  float* op = out + (((size_t)n * 4 * C + 4 * c) * Ho + h) * Wo + w;
  op[0]      = 0.25f * (a + b + cc + d);
  op[cs]     = 0.25f * (a + b - cc - d) + 0.5f;
  op[2 * cs] = 0.25f * (a - b + cc - d) + 0.5f;
  op[3 * cs] = 0.25f * (a - b - cc + d) + 0.5f;
}

// ---------------- Haar inverse (NCHW fp32, channel-offset write) ------------
__global__ void iwt_kernel(const float* __restrict__ v, float* __restrict__ out,
                           int C, int H, int W, int c_off, int Ctot, int total) {
  int idx = blockIdx.x * 256 + threadIdx.x;
  if (idx >= total) return;
  int w = idx % W; int t = idx / W;
  int h = t % H; t /= H;
  int c = t % C; int n = t / C;
  size_t cs = (size_t)H * W;
  const float* vp = v + (((size_t)n * 4 * C + 4 * c) * H + h) * W + w;
  float v0 = vp[0];
  float v1 = 2.f * vp[cs] - 1.f;
  float v2 = 2.f * vp[2 * cs] - 1.f;
  float v3 = 2.f * vp[3 * cs] - 1.f;
  int Wo = 2 * W;
  float* op = out + (((size_t)n * Ctot + c_off + c) * (2 * H) + 2 * h) * (size_t)Wo + 2 * w;
  op[0]      = v0 + 0.5f * ( v1 + v2 + v3);
  op[1]      = v0 + 0.5f * ( v1 - v2 - v3);
  op[Wo]     = v0 + 0.5f * (-v1 + v2 - v3);
  op[Wo + 1] = v0 + 0.5f * (-v1 - v2 + v3);
}

// ---------------- concat first-part copy ----------------
__global__ void copycat_kernel(const float* __restrict__ src, float* __restrict__ dst,
                               int C, int HW, int Ctot, int total) {
  int idx = blockIdx.x * 256 + threadIdx.x;
  if (idx >= total) return;
  int p = idx % HW; int t = idx / HW;
  int c = t % C; int n = t / C;
  dst[((size_t)n * Ctot + c) * HW + p] = src[idx];
}

// ---------------- NCHW fp32 -> padded NHWC f16 (LDS transpose) --------------
__global__ __launch_bounds__(256) void to_nhwc_pad_kernel(const float* __restrict__ in,
                                                          f16* __restrict__ out,
                                                          int C, int H, int W) {
  __shared__ f16 sm[32][264];
  int HW = H * W;
  int p0 = blockIdx.x * 256, c0 = blockIdx.y * 32, n = blockIdx.z;
  int t = threadIdx.x;
  const float* ip = in + ((size_t)n * C + c0) * HW + p0;
#pragma unroll 8
  for (int r = 0; r < 32; ++r) sm[r][t] = (f16)ip[(size_t)r * HW + t];
  __syncthreads();
#pragma unroll
  for (int i = 0; i < 4; ++i) {
    int c = t + i * 256;
    int pl = c >> 2, cio = (c & 3) * 8;
    f16x8 v;
#pragma unroll
    for (int u = 0; u < 8; ++u) v[u] = sm[cio + u][pl];
    int p = p0 + pl; int y = p / W; int x = p - y * W;
    *(f16x8*)(out + (((size_t)n * (H + 2) + y + 1) * (W + 2) + x + 1) * C + c0 + cio) = v;
  }
}

// ---------------- GN-apply + NCHW -> padded NHWC f16 (LDS transpose) --------
__global__ __launch_bounds__(256) void gn_nhwc_kernel(
    const float* __restrict__ in, const float* __restrict__ stats,
    const float* __restrict__ gamma, const float* __restrict__ beta,
    f16* __restrict__ out, int C, int H, int W, int G) {
  __shared__ f16 sm[32][264];
  int HW = H * W;
  int p0 = blockIdx.x * 256, c0 = blockIdx.y * 32, n = blockIdx.z;
  int t = threadIdx.x;
  int cpg = C / G;
  const float* ip = in + ((size_t)n * C + c0) * HW + p0;
#pragma unroll 8
  for (int r = 0; r < 32; ++r) {
    int c = c0 + r; int g = c / cpg;
    float mean = stats[(n * G + g) * 2], inv = stats[(n * G + g) * 2 + 1];
    float ga = gamma[c], be = beta[c];
    sm[r][t] = (f16)((ip[(size_t)r * HW + t] - mean) * inv * ga + be);
  }
  __syncthreads();
#pragma unroll
  for (int i = 0; i < 4; ++i) {
    int c = t + i * 256;
    int pl = c >> 2, cio = (c & 3) * 8;
    f16x8 v;
#pragma unroll
    for (int u = 0; u < 8; ++u) v[u] = sm[cio + u][pl];
    int p = p0 + pl; int y = p / W; int x = p - y * W;
    *(f16x8*)(out + (((size_t)n * (H + 2) + y + 1) * (W + 2) + x + 1) * C + c0 + cio) = v;
  }
}

// ---------------- fused final iwt + 1x1 ws-conv ----------------
__global__ void iwt_final_kernel(const float* __restrict__ v, const float* __restrict__ w,
                                 float* __restrict__ out, int total) {
  int idx = blockIdx.x * 256 + threadIdx.x;
  if (idx >= total) return;  // NB*128*128
  int ww = idx % 128; int t = idx / 128;
  int hh = t % 128; int n = t / 128;
  size_t cs = (size_t)128 * 128;
  float y0[3], y1[3], y2[3], y3[3];
#pragma unroll
  for (int c = 0; c < 3; ++c) {
    const float* vp = v + ((size_t)n * 12 + 4 * c) * cs + (size_t)hh * 128 + ww;
    float v0 = vp[0];
    float v1 = 2.f * vp[cs] - 1.f, v2 = 2.f * vp[2 * cs] - 1.f, v3 = 2.f * vp[3 * cs] - 1.f;
    y0[c] = v0 + 0.5f * ( v1 + v2 + v3);
    y1[c] = v0 + 0.5f * ( v1 - v2 - v3);
    y2[c] = v0 + 0.5f * (-v1 + v2 - v3);
    y3[c] = v0 + 0.5f * (-v1 - v2 + v3);
  }
  float w0 = w[0], w1 = w[1], w2 = w[2], w3 = w[3], w4 = w[4], w5 = w[5];
  size_t ocs = (size_t)256 * 256;
  float* o0 = out + (size_t)n * 2 * ocs + (size_t)(2 * hh) * 256 + 2 * ww;
  o0[0]   = w0 * y0[0] + w1 * y0[1] + w2 * y0[2];
  o0[1]   = w0 * y1[0] + w1 * y1[1] + w2 * y1[2];
  o0[256] = w0 * y2[0] + w1 * y2[1] + w2 * y2[2];
  o0[257] = w0 * y3[0] + w1 * y3[1] + w2 * y3[2];
  float* o1 = o0 + ocs;
  o1[0]   = w3 * y0[0] + w4 * y0[1] + w5 * y0[2];
  o1[1]   = w3 * y1[0] + w4 * y1[1] + w5 * y1[2];
  o1[256] = w3 * y2[0] + w4 * y2[1] + w5 * y2[2];
  o1[257] = w3 * y3[0] + w4 * y3[1] + w5 * y3[2];
}

// ---------------- conv_mfma5: 128x128x64, split-K = gridDim.z ----------------
__global__ __launch_bounds__(256) void conv_mfma5_kernel(
    const f16* __restrict__ A, const f16* __restrict__ Wp,
    f16* __restrict__ part, int Cin, int H, int W, int Cout, int HW) {
  constexpr int BM = 128, BN = 128, BK = 64;
  __shared__ f16 Asm[BM * BK];
  __shared__ f16 Bsm[BN * BK];

  const int tid = threadIdx.x;
  const int w = tid >> 6, lane = tid & 63;
  const int m0 = blockIdx.x * BM;
  const int co0 = blockIdx.y * BN;
  const int Wp2 = W + 2;

  const f16* gA[4]; const f16* gB[4];
  int lOff[4];
#pragma unroll
  for (int e = 0; e < 4; ++e) {
    int c = e * 256 + tid;
    int r = c >> 3, j = c & 7;
    int jx = j ^ (r & 7);
    int m = m0 + r; int n = m / HW; int p = m - n * HW;
    int y = p / W; int x = p - y * W;
    gA[e] = A + (((size_t)n * (H + 2) + y + 1) * Wp2 + (x + 1)) * Cin + jx * 8;
    gB[e] = Wp + (size_t)(co0 + r) * Cin + jx * 8;
    lOff[e] = (e * 256 + w * 64) * 8;
  }

  const int wm = w & 1, wn = w >> 1;
  const int lr = lane & 15, quad = lane >> 4;
  int aoffs[4][2], boffs[4][2];
#pragma unroll
  for (int i = 0; i < 4; ++i)
#pragma unroll
    for (int kk = 0; kk < 2; ++kk) {
      int r = wm * 64 + i * 16 + lr;
      int cidx = kk * 4 + quad;
      aoffs[i][kk] = (r * 8 + (cidx ^ (r & 7))) * 8;
      int rb = wn * 64 + i * 16 + lr;
      boffs[i][kk] = (rb * 8 + (cidx ^ (rb & 7))) * 8;
    }

  f32x4 acc[4][4];
#pragma unroll
  for (int i = 0; i < 4; ++i)
#pragma unroll
    for (int j = 0; j < 4; ++j) acc[i][j] = (f32x4){0.f, 0.f, 0.f, 0.f};

  const int kpt = Cin >> 6;
  const int nit = (9 * kpt) / gridDim.z;
  const size_t bstride = (size_t)Cout * Cin;

  int it0 = blockIdx.z * nit;
  int tap = it0 / kpt, kc = (it0 - tap * kpt) << 6;

  for (int ii = 0; ii < nit; ++ii) {
    int dy = tap / 3 - 1, dx = tap % 3 - 1;
    long offA = ((long)dy * Wp2 + dx) * Cin + kc;
    long offB = (long)tap * bstride + kc;
    __syncthreads();
#pragma unroll
    for (int e = 0; e < 4; ++e) {
      LLDS16(gA[e] + offA, Asm + lOff[e]);
      LLDS16(gB[e] + offB, Bsm + lOff[e]);
    }
    __syncthreads();

    f16x8 af[4][2], bf[4][2];
#pragma unroll
    for (int i = 0; i < 4; ++i)
#pragma unroll
      for (int kk = 0; kk < 2; ++kk) {
        af[i][kk] = *(const f16x8*)&Asm[aoffs[i][kk]];
        bf[i][kk] = *(const f16x8*)&Bsm[boffs[i][kk]];
      }
#pragma unroll
    for (int kk = 0; kk < 2; ++kk)
#pragma unroll
      for (int i = 0; i < 4; ++i)
#pragma unroll
        for (int j = 0; j < 4; ++j)
          acc[i][j] = __builtin_amdgcn_mfma_f32_16x16x32_f16(af[i][kk], bf[j][kk], acc[i][j], 0, 0, 0);

    kc += 64;
    if (kc == Cin) { kc = 0; ++tap; }
  }

  const size_t pbase = (size_t)blockIdx.z * NB * Cout * HW;
#pragma unroll
  for (int i = 0; i < 4; ++i) {
    int mg = m0 + wm * 64 + i * 16 + quad * 4;
    int n = mg / HW, p = mg - n * HW;
#pragma unroll
    for (int j = 0; j < 4; ++j) {
      int co = co0 + wn * 64 + j * 16 + lr;
      f32x4 v = acc[i][j];
      f16x4 h;
#pragma unroll
      for (int r = 0; r < 4; ++r) h[r] = (f16)v[r];
      *(f16x4*)&part[pbase + ((size_t)n * Cout + co) * HW + p] = h;
    }
  }
}

// ---------------- reduce S partials + bias (+add) (+lrelu) -> fp32 ----------
__global__ __launch_bounds__(256) void reduceS_kernel(
    const f16* __restrict__ part, const float* __restrict__ bias,
    const float* __restrict__ add, float* __restrict__ out,
    int Cout, int HW, int S, int do_lrelu, int total4) {
  int idx = blockIdx.x * 256 + threadIdx.x;
  if (idx >= total4) return;
  size_t sstride = (size_t)NB * Cout * HW;
  int hw4 = HW >> 2;
  int p4 = idx % hw4; int t = idx / hw4;
  int c = t % Cout;
  size_t eoff = (size_t)t * HW + p4 * 4;
  float b = bias[c];
  f32x4 o = {b, b, b, b};
  for (int s = 0; s < S; ++s) {
    f16x4 a = *(const f16x4*)(part + s * sstride + eoff);
#pragma unroll
    for (int r = 0; r < 4; ++r) o[r] += (float)a[r];
  }
  if (add) {
    f32x4 av = *(const f32x4*)(add + eoff);
#pragma unroll
    for (int r = 0; r < 4; ++r) o[r] += av[r];
  }
  if (do_lrelu)
#pragma unroll
    for (int r = 0; r < 4; ++r) o[r] = o[r] > 0.f ? o[r] : 0.2f * o[r];
  *(f32x4*)(out + eoff) = o;
}

// ---------------- conv_mfma2: 128x64x64 single-buffer (Cout=64) ----------
__global__ __launch_bounds__(256) void conv_mfma2_kernel(
    const f16* __restrict__ A, const f16* __restrict__ Wp,
    const float* __restrict__ bias, float* __restrict__ out,
    int Cin, int H, int W, int Cout, int HW, int do_lrelu) {
  constexpr int BM = 128, BN = 64, BK = 64;
  __shared__ f16 Asm[BM * BK];
  __shared__ f16 Bsm[BN * BK];

  const int tid = threadIdx.x;
  const int w = tid >> 6, lane = tid & 63;
  const int m0 = blockIdx.x * BM;
  const int co0 = blockIdx.y * BN;
  const int Wp2 = W + 2;

  const f16* gA[4];
  int lAoff[4];
#pragma unroll
  for (int e = 0; e < 4; ++e) {
    int c = e * 256 + tid;
    int r = c >> 3, j = c & 7;
    int jx = j ^ (r & 7);
    int m = m0 + r; int n = m / HW; int p = m - n * HW;
    int y = p / W; int x = p - y * W;
    gA[e] = A + (((size_t)n * (H + 2) + y + 1) * Wp2 + (x + 1)) * Cin + jx * 8;
    lAoff[e] = (e * 256 + w * 64) * 8;
  }
  const f16* gB[2];
  int lBoff[2];
#pragma unroll
  for (int e = 0; e < 2; ++e) {
    int c = e * 256 + tid;
    int r = c >> 3, j = c & 7;
    int jx = j ^ (r & 7);
    gB[e] = Wp + (size_t)(co0 + r) * Cin + jx * 8;
    lBoff[e] = (e * 256 + w * 64) * 8;
  }

  const int wm = w & 1, wn = w >> 1;
  const int lr = lane & 15, quad = lane >> 4;
  int aoffs[4][2], boffs[2][2];
#pragma unroll
  for (int i = 0; i < 4; ++i)
#pragma unroll
    for (int kk = 0; kk < 2; ++kk) {
      int r = wm * 64 + i * 16 + lr;
      int cidx = kk * 4 + quad;
      aoffs[i][kk] = (r * 8 + (cidx ^ (r & 7))) * 8;
    }
#pragma unroll
  for (int jn = 0; jn < 2; ++jn)
#pragma unroll
    for (int kk = 0; kk < 2; ++kk) {
      int rb = wn * 32 + jn * 16 + lr;
      int cidx = kk * 4 + quad;
      boffs[jn][kk] = (rb * 8 + (cidx ^ (rb & 7))) * 8;
    }

  f32x4 acc[4][2];
#pragma unroll
  for (int i = 0; i < 4; ++i)
#pragma unroll
    for (int jn = 0; jn < 2; ++jn) acc[i][jn] = (f32x4){0.f, 0.f, 0.f, 0.f};

  for (int tap = 0; tap < 9; ++tap) {
    const int dy = tap / 3 - 1, dx = tap % 3 - 1;
    const long tapA = ((long)dy * Wp2 + dx) * Cin;
    const long tapB = (size_t)tap * Cout * Cin;
    for (int kc = 0; kc < Cin; kc += BK) {
      __syncthreads();
#pragma unroll
      for (int e = 0; e < 4; ++e) LLDS16(gA[e] + tapA + kc, Asm + lAoff[e]);
#pragma unroll
      for (int e = 0; e < 2; ++e) LLDS16(gB[e] + tapB + kc, Bsm + lBoff[e]);
      __syncthreads();

      f16x8 af[4][2], bf[2][2];
#pragma unroll
      for (int i = 0; i < 4; ++i)
#pragma unroll
        for (int kk = 0; kk < 2; ++kk) af[i][kk] = *(const f16x8*)&Asm[aoffs[i][kk]];
#pragma unroll
      for (int jn = 0; jn < 2; ++jn)
#pragma unroll
        for (int kk = 0; kk < 2; ++kk) bf[jn][kk] = *(const f16x8*)&Bsm[boffs[jn][kk]];
#pragma unroll
      for (int kk = 0; kk < 2; ++kk)
#pragma unroll
        for (int i = 0; i < 4; ++i)
#pragma unroll
          for (int jn = 0; jn < 2; ++jn)
            acc[i][jn] = __builtin_amdgcn_mfma_f32_16x16x32_f16(af[i][kk], bf[jn][kk], acc[i][jn], 0, 0, 0);
    }
  }

#pragma unroll
  for (int i = 0; i < 4; ++i) {
    int mg = m0 + wm * 64 + i * 16 + quad * 4;
    int n = mg / HW, p = mg - n * HW;
#pragma unroll
    for (int jn = 0; jn < 2; ++jn) {
      int co = co0 + wn * 32 + jn * 16 + lr;
      float b = bias[co];
      f32x4 v = acc[i][jn];
#pragma unroll
      for (int r = 0; r < 4; ++r) {
        float u = v[r] + b;
        v[r] = (do_lrelu && u < 0.f) ? 0.2f * u : u;
      }
      *(f32x4*)&out[((size_t)n * Cout + co) * HW + p] = v;
    }
  }
}

// ---------------- direct 3x3 conv, register-blocked over Cout --------------
// block: 16x16 spatial tile, CO outputs per thread (all of Cout typically).
template <int CO, int CIC>
__global__ __launch_bounds__(256) void conv3x3_kernel(
    const float* __restrict__ in, const float* __restrict__ wgt,
    const float* __restrict__ bias, float* __restrict__ out,
    int Cin, int H, int W, int Cout, int do_lrelu) {
  __shared__ float sm[CIC][18][18];
  int tiles_x = W >> 4;
  int bt = blockIdx.x;
  int tx0 = (bt % tiles_x) << 4;
  int ty0 = (bt / tiles_x) << 4;
  int co0 = blockIdx.y * CO;
  int n = blockIdx.z;
  int tid = threadIdx.x;
  int lx = tid & 15, ly = tid >> 4;

  float acc[CO];
#pragma unroll
  for (int i = 0; i < CO; i++) acc[i] = 0.f;

  const float* inb = in + (size_t)n * Cin * H * W;

  for (int ci0 = 0; ci0 < Cin; ci0 += CIC) {
    __syncthreads();
    for (int idx = tid; idx < CIC * 324; idx += 256) {
      int ci = idx / 324;
      int r = idx - ci * 324;
      int gy = r / 18, gx = r - gy * 18;
      int iy = ty0 + gy - 1, ix = tx0 + gx - 1;
      float v = 0.f;
      if ((unsigned)iy < (unsigned)H && (unsigned)ix < (unsigned)W)
        v = inb[((size_t)(ci0 + ci)) * H * W + (size_t)iy * W + ix];
      sm[ci][gy][gx] = v;
    }
    __syncthreads();
#pragma unroll
    for (int ci = 0; ci < CIC; ci++) {
      float x00 = sm[ci][ly][lx],     x01 = sm[ci][ly][lx + 1],     x02 = sm[ci][ly][lx + 2];
      float x10 = sm[ci][ly + 1][lx], x11 = sm[ci][ly + 1][lx + 1], x12 = sm[ci][ly + 1][lx + 2];
      float x20 = sm[ci][ly + 2][lx], x21 = sm[ci][ly + 2][lx + 1], x22 = sm[ci][ly + 2][lx + 2];
      const float* wp = wgt + ((size_t)co0 * Cin + (ci0 + ci)) * 9;
#pragma unroll
      for (int co = 0; co < CO; co++) {
        const float* wc = wp + (size_t)co * Cin * 9;  // wave-uniform -> s_load
        float a = acc[co];
        a = fmaf(wc[0], x00, a); a = fmaf(wc[1], x01, a); a = fmaf(wc[2], x02, a);
        a = fmaf(wc[3], x10, a); a = fmaf(wc[4], x11, a); a = fmaf(wc[5], x12, a);
        a = fmaf(wc[6], x20, a); a = fmaf(wc[7], x21, a); a = fmaf(wc[8], x22, a);
        acc[co] = a;
      }
    }
  }

  int oy = ty0 + ly, ox = tx0 + lx;
#pragma unroll
  for (int co = 0; co < CO; co++) {
    float v = acc[co] + bias[co0 + co];
    if (do_lrelu) v = v > 0.f ? v : 0.2f * v;
    out[(((size_t)n * Cout + co0 + co) * H + oy) * W + ox] = v;
  }
}

// ---------------- group norm: stats / combine / apply ----------------
__global__ __launch_bounds__(256) void gn_stats_kernel(const float* __restrict__ x,
                                                       float* __restrict__ part,
                                                       int C, int HW, int G, int SPLIT) {
  __shared__ float red[512];
  int gs = blockIdx.x;
  int g = gs / SPLIT, s = gs - g * SPLIT;
  int n = blockIdx.y;
  int cpg = C / G;
  int len = cpg * HW;
  int chunk = len / SPLIT;
  size_t base = ((size_t)n * C + (size_t)g * cpg) * HW + (size_t)s * chunk;
  const f32x4* xp = (const f32x4*)(x + base);
  int chunk4 = chunk >> 2;
  float sm = 0.f, s2 = 0.f;
  for (int i = threadIdx.x; i < chunk4; i += 256) {
    f32x4 v = xp[i];
    sm += v.x + v.y + v.z + v.w;
    s2 += v.x * v.x + v.y * v.y + v.z * v.z + v.w * v.w;
  }
  red[threadIdx.x] = sm; red[256 + threadIdx.x] = s2;
  __syncthreads();
  for (int st = 128; st > 0; st >>= 1) {
    if (threadIdx.x < st) {
      red[threadIdx.x] += red[threadIdx.x + st];
      red[256 + threadIdx.x] += red[256 + threadIdx.x + st];
    }
    __syncthreads();
  }
  if (threadIdx.x == 0) {
    int o = ((n * G + g) * SPLIT + s) * 2;
    part[o] = red[0]; part[o + 1] = red[256];
  }
}

__global__ void gn_combine_kernel(const float* __restrict__ part, float* __restrict__ stats,
                                  int SPLIT, int len, int total) {
  int idx = blockIdx.x * 256 + threadIdx.x;
  if (idx >= total) return;
  float s = 0.f, s2 = 0.f;
  for (int i = 0; i < SPLIT; ++i) { s += part[(idx * SPLIT + i) * 2]; s2 += part[(idx * SPLIT + i) * 2 + 1]; }
  float mean = s / (float)len;
  float var = s2 / (float)len - mean * mean;
  if (var < 0.f) var = 0.f;
  stats[idx * 2] = mean;
  stats[idx * 2 + 1] = rsqrtf(var + 1e-5f);
}

__global__ __launch_bounds__(256) void gn_apply_kernel(float* __restrict__ x,
                                                       const float* __restrict__ stats,
                                                       const float* __restrict__ gamma,
                                                       const float* __restrict__ beta,
                                                       int C, int HW, int G, int total4) {
  int idx = blockIdx.x * 256 + threadIdx.x;
  if (idx >= total4) return;
  int hw4 = HW >> 2;
  int p4 = idx % hw4; int t = idx / hw4;
  int c = t % C; int n = t / C;
  int cpg = C / G; int g = c / cpg;
  float mean = stats[(n * G + g) * 2];
  float inv  = stats[(n * G + g) * 2 + 1];
  float ga = gamma[c], be = beta[c];
  f32x4* xp = (f32x4*)(x + ((size_t)t * HW)) + p4;
  f32x4 v = *xp;
#pragma unroll
  for (int r = 0; r < 4; ++r) v[r] = (v[r] - mean) * inv * ga + be;
  *xp = v;
}

// ---------------------------------------------------------------------------

extern "C" void kernel_launch(void* const* d_in, const int* in_sizes, int n_in,
                              void* d_out, int out_size, void* d_ws, size_t ws_size,
                              hipStream_t stream) {
  const float* x        = (const float*)d_in[0];
  const float* conv1_w  = (const float*)d_in[1];
  const float* conv1_b  = (const float*)d_in[2];
  const float* conv2_w  = (const float*)d_in[3];
  const float* conv2_b  = (const float*)d_in[4];
  const float* conv3_w  = (const float*)d_in[5];
  const float* conv3_b  = (const float*)d_in[6];
  const float* conv4_w  = (const float*)d_in[7];
  const float* conv4_b  = (const float*)d_in[8];
  const float* convd1_w = (const float*)d_in[9];
  const float* convd1_b = (const float*)d_in[10];
  const float* convd2_w = (const float*)d_in[11];
  const float* convd2_b = (const float*)d_in[12];
  const float* convd3_w = (const float*)d_in[13];
  const float* convd3_b = (const float*)d_in[14];
  const float* convd4_w = (const float*)d_in[15];
  const float* convd4_b = (const float*)d_in[16];
  const float* final_w  = (const float*)d_in[17];
  const float* gn1_w = (const float*)d_in[18];
  const float* gn1_b = (const float*)d_in[19];
  const float* gn2_w = (const float*)d_in[20];
  const float* gn2_b = (const float*)d_in[21];
  const float* gn3_w = (const float*)d_in[22];
  const float* gn3_b = (const float*)d_in[23];
  const float* gn4_w = (const float*)d_in[24];
  const float* gn4_b = (const float*)d_in[25];

  char* base = (char*)d_ws;
  size_t off = 0;
  auto allocB = [&](size_t bytes) { size_t o = off; off = (off + bytes + 255) & ~(size_t)255; return o; };

  size_t o_sw1  = allocB(16 * 108 * 4);
  size_t o_swd1 = allocB(12 * 144 * 4);
  size_t o_swd2 = allocB(16 * 288 * 4);
  size_t o_swf  = allocB(6 * 4);
  size_t o_pw2  = allocB((size_t)9 * 64 * 64 * 2);
  size_t o_pw3  = allocB((size_t)9 * 256 * 256 * 2);
  size_t o_pw4  = allocB((size_t)9 * 1024 * 1024 * 2);
  size_t o_pwd3 = allocB((size_t)9 * 64 * 128 * 2);
  size_t o_pwd4 = allocB((size_t)9 * 256 * 512 * 2);
  // R1: part (S=2, 16.8MB) | ah64 (8.9MB) | ah128 (17.8MB) — disjoint lifetimes
  size_t o_R1   = allocB((size_t)NB * 66 * 66 * 128 * 2);
  // R2: ah256 (9.5MB) | ah1k (10.6MB) | ah512 (18.9MB) — disjoint lifetimes
  size_t o_R2   = allocB((size_t)NB * 34 * 34 * 512 * 2);
  size_t o_gnp  = allocB(4096 * 4);
  size_t o_gns  = allocB(4096 * 4);
  size_t o_c1 = allocB((size_t)NB * 16 * 128 * 128 * 4);
  size_t o_c2 = allocB((size_t)NB * 64 * 64 * 64 * 4);
  size_t o_c3 = allocB((size_t)NB * 256 * 32 * 32 * 4);
  size_t o_w4 = allocB((size_t)NB * 1024 * 16 * 16 * 4);
  size_t o_t1 = allocB((size_t)NB * 1024 * 16 * 16 * 4);
  size_t o_t2 = allocB((size_t)NB * 512 * 32 * 32 * 4);

  if (off > ws_size) return;

  float* c1 = (float*)(base + o_c1);
  float* c2 = (float*)(base + o_c2);
  float* c3 = (float*)(base + o_c3);
  float* w4 = (float*)(base + o_w4);
  float* t1 = (float*)(base + o_t1);
  float* t2 = (float*)(base + o_t2);
  f16* part  = (f16*)(base + o_R1);
  f16* ah64  = (f16*)(base + o_R1);
  f16* ah128 = (f16*)(base + o_R1);
  f16* ah256 = (f16*)(base + o_R2);
  f16* ah1k  = (f16*)(base + o_R2);
  f16* ah512 = (f16*)(base + o_R2);
  f16* pw2 = (f16*)(base + o_pw2);
  f16* pw3 = (f16*)(base + o_pw3);
  f16* pw4 = (f16*)(base + o_pw4);
  f16* pwd3 = (f16*)(base + o_pwd3);
  f16* pwd4 = (f16*)(base + o_pwd4);
  float* gnp = (float*)(base + o_gnp);
  float* gns = (float*)(base + o_gns);

  // ---- upfront: zero halos of ah64 + ah256; weight prep ----
  {
    int n0 = NB * (2 * 66 + 2 * 64) * (64 / 8);
    int n1 = NB * (2 * 34 + 2 * 32) * (256 / 8);
    int tot = n0 + n1;
    halo2_kernel<<<(tot + 255) / 256, 256, 0, stream>>>(ah64, 64, 64, 64, n0,
                                                        ah256, 256, 32, 32, tot);
  }
  ws_all_kernel<<<46, 256, 0, stream>>>(conv1_w, (float*)(base + o_sw1),
                                        convd1_w, (float*)(base + o_swd1),
                                        convd2_w, (float*)(base + o_swd2),
                                        final_w, (float*)(base + o_swf));
  ws_f16_all_kernel<<<1664, 256, 0, stream>>>(conv2_w, pw2, conv3_w, pw3, conv4_w, pw4,
                                              convd3_w, pwd3, convd4_w, pwd4);

  auto gn_sc = [&](const float* xb, int C, int HW, int G) {
    int SPLIT = 2048 / (G * NB);
    if (SPLIT < 1) SPLIT = 1;
    int len = (C / G) * HW;
    dim3 gsd(G * SPLIT, NB);
    gn_stats_kernel<<<gsd, 256, 0, stream>>>(xb, gnp, C, HW, G, SPLIT);
    int tot = NB * G;
    gn_combine_kernel<<<(tot + 255) / 256, 256, 0, stream>>>(gnp, gns, SPLIT, len, tot);
  };
  auto gn_full = [&](float* xb, const float* g, const float* b, int C, int HW, int G) {
    gn_sc(xb, C, HW, G);
    int total4 = (NB * C * HW) >> 2;
    gn_apply_kernel<<<(total4 + 255) / 256, 256, 0, stream>>>(xb, gns, g, b, C, HW, G, total4);
  };
  auto prep_nhwc = [&](const float* in, f16* ah, int C, int H, int W, int zero) {
    if (zero) {
      int total8 = NB * (2 * (W + 2) + 2 * H) * (C / 8);
      zero_halo_kernel<<<(total8 + 255) / 256, 256, 0, stream>>>(ah, C, H, W, total8);
    }
    dim3 g((H * W) / 256, C / 32, NB);
    to_nhwc_pad_kernel<<<g, 256, 0, stream>>>(in, ah, C, H, W);
  };
  auto cm5 = [&](const f16* a, const f16* wt, const float* b, float* dest, const float* add,
                 int Cin, int Hs, int Ws, int Cout, int lr) {
    dim3 g((NB * Hs * Ws) / 128, Cout / 128, 2);
    conv_mfma5_kernel<<<g, 256, 0, stream>>>(a, wt, part, Cin, Hs, Ws, Cout, Hs * Ws);
    int total4 = (NB * Cout * Hs * Ws) >> 2;
    reduceS_kernel<<<(total4 + 255) / 256, 256, 0, stream>>>(part, b, add, dest,
                                                             Cout, Hs * Ws, 2, lr, total4);
  };
  auto cm2 = [&](const f16* a, const f16* wt, const float* b, float* o,
                 int Cin, int Hs, int Ws, int Cout, int lr) {
    dim3 g((NB * Hs * Ws) / 128, Cout / 64);
    conv_mfma2_kernel<<<g, 256, 0, stream>>>(a, wt, b, o, Cin, Hs, Ws, Cout, Hs * Ws, lr);
  };
  auto launch_wt = [&](const float* in, float* out, int C, int Ho, int Wo) {
    int total = NB * C * Ho * Wo;
    wt_kernel<<<(total + 255) / 256, 256, 0, stream>>>(in, out, C, Ho, Wo, total);
  };
  auto launch_iwt = [&](const float* v, float* out, int C, int H, int W, int c_off, int Ctot) {
    int total = NB * C * H * W;
    iwt_kernel<<<(total + 255) / 256, 256, 0, stream>>>(v, out, C, H, W, c_off, Ctot, total);
  };
  auto launch_copycat = [&](const float* src, float* dst, int C, int HW, int Ctot) {
    int total = NB * C * HW;
    copycat_kernel<<<(total + 255) / 256, 256, 0, stream>>>(src, dst, C, HW, Ctot, total);
  };

  // ==== encoder ====
  launch_wt(x, t1, 3, 128, 128);                                    // w1 -> t1 (12@128^2)
  {  // c1 = lrelu(conv1(w1)) — CO=16 register-blocked
    dim3 g(64, 1, NB);
    conv3x3_kernel<16, 4><<<g, 256, 0, stream>>>(t1, (float*)(base + o_sw1), conv1_b,
                                                 c1, 12, 128, 128, 16, 1);
  }
  gn_full(c1, gn1_w, gn1_b, 16, 128 * 128, 2);

  launch_wt(c1, t1, 16, 64, 64);                                    // w2 -> t1 (64@64^2)
  prep_nhwc(t1, ah64, 64, 64, 64, 0);                               // halo pre-zeroed
  cm2(ah64, pw2, conv2_b, c2, 64, 64, 64, 64, 1);                   // c2
  gn_full(c2, gn2_w, gn2_b, 64, 64 * 64, 8);

  launch_wt(c2, t1, 64, 32, 32);                                    // w3 -> t1 (256@32^2)
  prep_nhwc(t1, ah256, 256, 32, 32, 0);                             // halo pre-zeroed
  cm5(ah256, pw3, conv3_b, c3, nullptr, 256, 32, 32, 256, 1);       // c3
  gn_full(c3, gn3_w, gn3_b, 256, 32 * 32, 32);

  launch_wt(c3, w4, 256, 16, 16);                                   // w4 (1024@16^2 fp32)
  prep_nhwc(w4, ah1k, 1024, 16, 16, 1);                             // R2 reused -> zero halo

  cm5(ah1k, pw4, conv4_b, t1, nullptr, 1024, 16, 16, 1024, 1);      // c4 -> t1
  gn_sc(t1, 1024, 256, 128);
  {
    dim3 g(1, 32, NB);
    gn_nhwc_kernel<<<g, 256, 0, stream>>>(t1, gns, gn4_w, gn4_b, ah1k, 1024, 16, 16, 128);
  }
  cm5(ah1k, pw4, conv4_b, t2, nullptr, 1024, 16, 16, 1024, 1);      // c5 -> t2
  gn_sc(t2, 1024, 256, 128);
  {
    dim3 g(1, 32, NB);
    gn_nhwc_kernel<<<g, 256, 0, stream>>>(t2, gns, gn4_w, gn4_b, ah1k, 1024, 16, 16, 128);
  }
  cm5(ah1k, pw4, conv4_b, t1, w4, 1024, 16, 16, 1024, 1);           // ic4 = lrelu(c6+w4) -> t1

  // ==== decoder ====
  launch_copycat(c3, t2, 256, 32 * 32, 512);                        // iw4 -> t2 (fp32)
  launch_iwt(t1, t2, 256, 16, 16, 256, 512);
  prep_nhwc(t2, ah512, 512, 32, 32, 1);                             // R2 reused -> zero halo
  cm5(ah512, pwd4, convd4_b, t1, nullptr, 512, 32, 32, 256, 1);     // ic3 -> t1
  gn_full(t1, gn3_w, gn3_b, 256, 32 * 32, 32);

  launch_copycat(c2, t2, 64, 64 * 64, 128);                         // iw3 -> t2
  launch_iwt(t1, t2, 64, 32, 32, 64, 128);
  prep_nhwc(t2, ah128, 128, 64, 64, 1);                             // R1 reused -> zero halo
  cm2(ah128, pwd3, convd3_b, t1, 128, 64, 64, 64, 1);               // ic2 -> t1
  gn_full(t1, gn2_w, gn2_b, 64, 64 * 64, 8);

  launch_copycat(c1, t2, 16, 128 * 128, 32);                        // iw2 -> t2
  launch_iwt(t1, t2, 16, 64, 64, 16, 32);
  {  // ic1 = lrelu(convd2(iw2)) -> t1 — CO=16
    dim3 g(64, 1, NB);
    conv3x3_kernel<16, 4><<<g, 256, 0, stream>>>(t2, (float*)(base + o_swd2), convd2_b,
                                                 t1, 32, 128, 128, 16, 1);
  }
  gn_full(t1, gn1_w, gn1_b, 16, 128 * 128, 2);
  {  // iw1 = lrelu(convd1(ic1)) -> t2 — CO=12
    dim3 g(64, 1, NB);
    conv3x3_kernel<12, 4><<<g, 256, 0, stream>>>(t1, (float*)(base + o_swd1), convd1_b,
                                                 t2, 16, 128, 128, 12, 1);
  }
  {  // y = final_conv(iwt(iw1)) -> d_out
    int total = NB * 128 * 128;
    iwt_final_kernel<<<(total + 255) / 256, 256, 0, stream>>>(t2, (float*)(base + o_swf),
                                                              (float*)d_out, total);
  }
}

// Round 10
// 943.015 us; speedup vs baseline: 1.2114x; 1.0868x over previous
//
#include <hip/hip_runtime.h>
#include <math.h>

// ---------------------------------------------------------------------------
// WaveletNet forward. conv_mfma6: 128x128x64 double-buffered (1 barrier/iter),
// split-K=2, 2 blocks/CU. GN via block-partials (no combine kernel); partials
// produced inline by reduceS / direct-conv epilogues; GN-apply inlined into
// decoder concat+iwt. N=16 fixed.
// ---------------------------------------------------------------------------

#define NB 16  // batch

typedef _Float16 f16;
typedef _Float16 f16x8 __attribute__((ext_vector_type(8)));
typedef _Float16 f16x4 __attribute__((ext_vector_type(4)));
typedef float f32x4 __attribute__((ext_vector_type(4)));
typedef unsigned int u32;

#define LLDS16(gp, lp)                                                          \
  __builtin_amdgcn_global_load_lds((const __attribute__((address_space(1))) u32*)(const void*)(gp), \
                                   (__attribute__((address_space(3))) u32*)(void*)(lp), 16, 0, 0)

// ---------------- weight standardization ----------------
__device__ __forceinline__ void ws_reduce(const float* wp, int fan, float* red,
                                          float& mean, float& inv) {
  float s = 0.f, s2 = 0.f;
  for (int i = threadIdx.x; i < fan; i += 256) { float v = wp[i]; s += v; s2 += v * v; }
  red[threadIdx.x] = s; red[256 + threadIdx.x] = s2;
  __syncthreads();
  for (int st = 128; st > 0; st >>= 1) {
    if (threadIdx.x < st) {
      red[threadIdx.x] += red[threadIdx.x + st];
      red[256 + threadIdx.x] += red[256 + threadIdx.x + st];
    }
    __syncthreads();
  }
  float sum = red[0], sumsq = red[256];
  mean = sum / (float)fan;
  float var = (sumsq - sum * mean) / (float)(fan - 1);
  if (var < 0.f) var = 0.f;
  inv = 1.0f / (sqrtf(var) + 1e-5f);
}

__global__ void ws_all_kernel(const float* w0, float* o0, const float* w1, float* o1,
                              const float* w2, float* o2, const float* w3, float* o3) {
  __shared__ float red[512];
  int b = blockIdx.x;
  const float* w; float* o; int fan, oi;
  if (b < 16)      { w = w0; o = o0; fan = 108; oi = b; }
  else if (b < 28) { w = w1; o = o1; fan = 144; oi = b - 16; }
  else if (b < 44) { w = w2; o = o2; fan = 288; oi = b - 28; }
  else             { w = w3; o = o3; fan = 3;   oi = b - 44; }
  const float* wp = w + (size_t)oi * fan;
  float mean, inv; ws_reduce(wp, fan, red, mean, inv);
  for (int i = threadIdx.x; i < fan; i += 256)
    o[(size_t)oi * fan + i] = (wp[i] - mean) * inv;
}

__global__ void ws_f16_all_kernel(const float* w0, f16* o0, const float* w1, f16* o1,
                                  const float* w2, f16* o2, const float* w3, f16* o3,
                                  const float* w4, f16* o4) {
  __shared__ float red[512];
  int b = blockIdx.x;
  const float* w; f16* o; int fan, Cin, Cout, oi;
  if (b < 64)        { w = w0; o = o0; fan = 576;  Cin = 64;   Cout = 64;   oi = b; }
  else if (b < 320)  { w = w1; o = o1; fan = 2304; Cin = 256;  Cout = 256;  oi = b - 64; }
  else if (b < 1344) { w = w2; o = o2; fan = 9216; Cin = 1024; Cout = 1024; oi = b - 320; }
  else if (b < 1408) { w = w3; o = o3; fan = 1152; Cin = 128;  Cout = 64;   oi = b - 1344; }
  else               { w = w4; o = o4; fan = 4608; Cin = 512;  Cout = 256;  oi = b - 1408; }
  const float* wp = w + (size_t)oi * fan;
  float mean, inv; ws_reduce(wp, fan, red, mean, inv);
  for (int i = threadIdx.x; i < fan; i += 256) {
    int ci = i / 9, tap = i - ci * 9;
    o[((size_t)tap * Cout + oi) * Cin + ci] = (f16)((wp[i] - mean) * inv);
  }
}

// ---------------- halo zero ----------------
__device__ __forceinline__ void halo_write(f16* buf, int C, int H, int W, int t) {
  int c8s = C >> 3;
  int c8 = t % c8s; int q = t / c8s;
  int P = 2 * (W + 2) + 2 * H;
  int b = q % P; int n = q / P;
  int y, x;
  if (b < W + 2) { y = 0; x = b; }
  else if (b < 2 * (W + 2)) { y = H + 1; x = b - (W + 2); }
  else { int bb = b - 2 * (W + 2); y = 1 + (bb >> 1); x = (bb & 1) ? (W + 1) : 0; }
  size_t a = (((size_t)n * (H + 2) + y) * (W + 2) + x) * C + c8 * 8;
  *(f16x8*)(buf + a) = (f16x8){0, 0, 0, 0, 0, 0, 0, 0};
}

__global__ void halo2_kernel(f16* b0, int c0, int h0, int w0, int n0,
                             f16* b1, int c1, int h1, int w1, int total) {
  int idx = blockIdx.x * 256 + threadIdx.x;
  if (idx >= total) return;
  if (idx < n0) halo_write(b0, c0, h0, w0, idx);
  else halo_write(b1, c1, h1, w1, idx - n0);
}

__global__ void zero_halo_kernel(f16* __restrict__ buf, int C, int H, int W, int total8) {
  int idx = blockIdx.x * 256 + threadIdx.x;
  if (idx >= total8) return;
  halo_write(buf, C, H, W, idx);
}

// ---------------- Haar forward (NCHW fp32) ----------------
__global__ void wt_kernel(const float* __restrict__ in, float* __restrict__ out,
                          int C, int Ho, int Wo, int total) {
  int idx = blockIdx.x * 256 + threadIdx.x;
  if (idx >= total) return;
  int w = idx % Wo; int t = idx / Wo;
  int h = t % Ho; t /= Ho;
  int c = t % C; int n = t / C;
  int Wi = 2 * Wo;
  const float* ip = in + (((size_t)n * C + c) * (2 * Ho) + 2 * h) * Wi + 2 * w;
  float a = ip[0], b = ip[1], cc = ip[Wi], d = ip[Wi + 1];
  size_t cs = (size_t)Ho * Wo;
  float* op = out + (((size_t)n * 4 * C + 4 * c) * Ho + h) * Wo + w;
  op[0]      = 0.25f * (a + b + cc + d);
  op[cs]     = 0.25f * (a + b - cc - d) + 0.5f;
  op[2 * cs] = 0.25f * (a - b + cc - d) + 0.5f;
  op[3 * cs] = 0.25f * (a - b - cc + d) + 0.5f;
}

// ---------------- fused concat + iwt (+optional inline GN on v) ------------
// out (N,2C,2Hh,2Wh): ch [0,C) = skip copy; [C,2C) = iwt(gn?(v)), v 4C@(Hh,Wh)
__global__ void concat_iwt_kernel(const float* __restrict__ skip, const float* __restrict__ v,
                                  float* __restrict__ out, const float* __restrict__ gnp,
                                  const float* __restrict__ gamma, const float* __restrict__ beta,
                                  int G, int Sg, int len, int C, int Hh, int Wh,
                                  int totalA, int total) {
  int idx = blockIdx.x * 256 + threadIdx.x;
  if (idx >= total) return;
  int W = 2 * Wh, H = 2 * Hh; int HWs = H * W;
  if (idx < totalA) {
    int p = idx % HWs; int t = idx / HWs; int c = t % C; int n = t / C;
    out[((size_t)n * 2 * C + c) * HWs + p] = skip[idx];
    return;
  }
  int i2 = idx - totalA;
  int w = i2 % Wh; int t = i2 / Wh; int h = t % Hh; t /= Hh;
  int c = t % C; int n = t / C;
  size_t cs = (size_t)Hh * Wh;
  const float* vp = v + (((size_t)n * 4 * C + 4 * c) * Hh + h) * Wh + w;
  float v0 = vp[0], v1 = vp[cs], v2 = vp[2 * cs], v3 = vp[3 * cs];
  if (gnp) {
    int cpg = (4 * C) / G;
    int g = (4 * c) / cpg;  // cpg=8 -> 4 consecutive ch in one group
    const float* pp = gnp + (size_t)((n * G + g) * Sg) * 2;
    float s = 0.f, s2 = 0.f;
    for (int i = 0; i < Sg; ++i) { s += pp[2 * i]; s2 += pp[2 * i + 1]; }
    float mean = s / (float)len;
    float var = s2 / (float)len - mean * mean;
    if (var < 0.f) var = 0.f;
    float inv = rsqrtf(var + 1e-5f);
    v0 = (v0 - mean) * inv * gamma[4 * c]     + beta[4 * c];
    v1 = (v1 - mean) * inv * gamma[4 * c + 1] + beta[4 * c + 1];
    v2 = (v2 - mean) * inv * gamma[4 * c + 2] + beta[4 * c + 2];
    v3 = (v3 - mean) * inv * gamma[4 * c + 3] + beta[4 * c + 3];
  }
  v1 = 2.f * v1 - 1.f; v2 = 2.f * v2 - 1.f; v3 = 2.f * v3 - 1.f;
  float* op = out + (((size_t)n * 2 * C + C + c) * H + 2 * h) * (size_t)W + 2 * w;
  op[0]     = v0 + 0.5f * ( v1 + v2 + v3);
  op[1]     = v0 + 0.5f * ( v1 - v2 - v3);
  op[W]     = v0 + 0.5f * (-v1 + v2 - v3);
  op[W + 1] = v0 + 0.5f * (-v1 - v2 + v3);
}

// ---------------- NCHW fp32 -> padded NHWC f16 (LDS transpose) --------------
__global__ __launch_bounds__(256) void to_nhwc_pad_kernel(const float* __restrict__ in,
                                                          f16* __restrict__ out,
                                                          int C, int H, int W) {
  __shared__ f16 sm[32][264];
  int HW = H * W;
  int p0 = blockIdx.x * 256, c0 = blockIdx.y * 32, n = blockIdx.z;
  int t = threadIdx.x;
  const float* ip = in + ((size_t)n * C + c0) * HW + p0;
#pragma unroll 8
  for (int r = 0; r < 32; ++r) sm[r][t] = (f16)ip[(size_t)r * HW + t];
  __syncthreads();
#pragma unroll
  for (int i = 0; i < 4; ++i) {
    int c = t + i * 256;
    int pl = c >> 2, cio = (c & 3) * 8;
    f16x8 v;
#pragma unroll
    for (int u = 0; u < 8; ++u) v[u] = sm[cio + u][pl];
    int p = p0 + pl; int y = p / W; int x = p - y * W;
    *(f16x8*)(out + (((size_t)n * (H + 2) + y + 1) * (W + 2) + x + 1) * C + c0 + cio) = v;
  }
}

// ---------------- GN-apply (partial-based) + NCHW->padded NHWC f16 ----------
__global__ __launch_bounds__(256) void gn_nhwc_kernel(
    const float* __restrict__ in, const float* __restrict__ gnp,
    const float* __restrict__ gamma, const float* __restrict__ beta,
    f16* __restrict__ out, int C, int H, int W, int G, int Sg, int len) {
  __shared__ f16 sm[32][264];
  int HW = H * W;
  int p0 = blockIdx.x * 256, c0 = blockIdx.y * 32, n = blockIdx.z;
  int t = threadIdx.x;
  int cpg = C / G;
  const float* ip = in + ((size_t)n * C + c0) * HW + p0;
#pragma unroll 8
  for (int r = 0; r < 32; ++r) {
    int c = c0 + r; int g = c / cpg;
    const float* pp = gnp + (size_t)((n * G + g) * Sg) * 2;
    float s = 0.f, s2 = 0.f;
    for (int i = 0; i < Sg; ++i) { s += pp[2 * i]; s2 += pp[2 * i + 1]; }
    float mean = s / (float)len;
    float var = s2 / (float)len - mean * mean;
    if (var < 0.f) var = 0.f;
    float inv = rsqrtf(var + 1e-5f);
    float ga = gamma[c], be = beta[c];
    sm[r][t] = (f16)((ip[(size_t)r * HW + t] - mean) * inv * ga + be);
  }
  __syncthreads();
#pragma unroll
  for (int i = 0; i < 4; ++i) {
    int c = t + i * 256;
    int pl = c >> 2, cio = (c & 3) * 8;
    f16x8 v;
#pragma unroll
    for (int u = 0; u < 8; ++u) v[u] = sm[cio + u][pl];
    int p = p0 + pl; int y = p / W; int x = p - y * W;
    *(f16x8*)(out + (((size_t)n * (H + 2) + y + 1) * (W + 2) + x + 1) * C + c0 + cio) = v;
  }
}

// ---------------- fused final iwt + 1x1 ws-conv ----------------
__global__ void iwt_final_kernel(const float* __restrict__ v, const float* __restrict__ w,
                                 float* __restrict__ out, int total) {
  int idx = blockIdx.x * 256 + threadIdx.x;
  if (idx >= total) return;  // NB*128*128
  int ww = idx % 128; int t = idx / 128;
  int hh = t % 128; int n = t / 128;
  size_t cs = (size_t)128 * 128;
  float y0[3], y1[3], y2[3], y3[3];
#pragma unroll
  for (int c = 0; c < 3; ++c) {
    const float* vp = v + ((size_t)n * 12 + 4 * c) * cs + (size_t)hh * 128 + ww;
    float v0 = vp[0];
    float v1 = 2.f * vp[cs] - 1.f, v2 = 2.f * vp[2 * cs] - 1.f, v3 = 2.f * vp[3 * cs] - 1.f;
    y0[c] = v0 + 0.5f * ( v1 + v2 + v3);
    y1[c] = v0 + 0.5f * ( v1 - v2 - v3);
    y2[c] = v0 + 0.5f * (-v1 + v2 - v3);
    y3[c] = v0 + 0.5f * (-v1 - v2 + v3);
  }
  float w0 = w[0], w1 = w[1], w2 = w[2], w3 = w[3], w4 = w[4], w5 = w[5];
  size_t ocs = (size_t)256 * 256;
  float* o0 = out + (size_t)n * 2 * ocs + (size_t)(2 * hh) * 256 + 2 * ww;
  o0[0]   = w0 * y0[0] + w1 * y0[1] + w2 * y0[2];
  o0[1]   = w0 * y1[0] + w1 * y1[1] + w2 * y1[2];
  o0[256] = w0 * y2[0] + w1 * y2[1] + w2 * y2[2];
  o0[257] = w0 * y3[0] + w1 * y3[1] + w2 * y3[2];
  float* o1 = o0 + ocs;
  o1[0]   = w3 * y0[0] + w4 * y0[1] + w5 * y0[2];
  o1[1]   = w3 * y1[0] + w4 * y1[1] + w5 * y1[2];
  o1[256] = w3 * y2[0] + w4 * y2[1] + w5 * y2[2];
  o1[257] = w3 * y3[0] + w4 * y3[1] + w5 * y3[2];
}

// ---------------- conv_mfma6: 128x128x64, dbuf, 1 barrier/iter, split-K -----
__global__ __launch_bounds__(256) void conv_mfma6_kernel(
    const f16* __restrict__ A, const f16* __restrict__ Wp,
    f16* __restrict__ part, int Cin, int H, int W, int Cout, int HW) {
  constexpr int CH = 128 * 64;  // f16 per buffer
  __shared__ f16 Asm[2 * CH];   // 32 KB
  __shared__ f16 Bsm[2 * CH];   // 32 KB

  const int tid = threadIdx.x;
  const int w = tid >> 6, lane = tid & 63;
  const int m0 = blockIdx.x * 128;
  const int co0 = blockIdx.y * 128;
  const int Wp2 = W + 2;

  const f16* gA[4]; const f16* gB[4];
  int lOff[4];
#pragma unroll
  for (int e = 0; e < 4; ++e) {
    int c = e * 256 + tid;
    int r = c >> 3, j = c & 7;
    int jx = j ^ (r & 7);
    int m = m0 + r; int n = m / HW; int p = m - n * HW;
    int y = p / W; int x = p - y * W;
    gA[e] = A + (((size_t)n * (H + 2) + y + 1) * Wp2 + (x + 1)) * Cin + jx * 8;
    gB[e] = Wp + (size_t)(co0 + r) * Cin + jx * 8;
    lOff[e] = (e * 256 + w * 64) * 8;  // wave-uniform
  }

  const int wm = w & 1, wn = w >> 1;
  const int lr = lane & 15, quad = lane >> 4;
  int aoffs[4][2], boffs[4][2];
#pragma unroll
  for (int i = 0; i < 4; ++i)
#pragma unroll
    for (int kk = 0; kk < 2; ++kk) {
      int r = wm * 64 + i * 16 + lr;
      int cidx = kk * 4 + quad;
      aoffs[i][kk] = (r * 8 + (cidx ^ (r & 7))) * 8;
      int rb = wn * 64 + i * 16 + lr;
      boffs[i][kk] = (rb * 8 + (cidx ^ (rb & 7))) * 8;
    }

  f32x4 acc[4][4];
#pragma unroll
  for (int i = 0; i < 4; ++i)
#pragma unroll
    for (int j = 0; j < 4; ++j) acc[i][j] = (f32x4){0.f, 0.f, 0.f, 0.f};

  const int kpt = Cin >> 6;
  const int nit = (9 * kpt) / gridDim.z;
  const int it0 = blockIdx.z * nit;
  const size_t bstride = (size_t)Cout * Cin;

  auto stageAB = [&](int it, int sel) {
    int tap = it / kpt, kk = it - tap * kpt;
    int dy = tap / 3 - 1, dx = tap % 3 - 1;
    long offA = ((long)dy * Wp2 + dx) * Cin + (kk << 6);
    long offB = (long)tap * bstride + (kk << 6);
    f16* ab = Asm + sel * CH;
    f16* bb = Bsm + sel * CH;
#pragma unroll
    for (int e = 0; e < 4; ++e) {
      LLDS16(gA[e] + offA, ab + lOff[e]);
      LLDS16(gB[e] + offB, bb + lOff[e]);
    }
  };

  stageAB(it0, 0);
  int sel = 0;
  for (int ii = 0; ii < nit; ++ii) {
    __syncthreads();  // drains prefetch (vmcnt) + prior reads (lgkm)
    if (ii + 1 < nit) stageAB(it0 + ii + 1, sel ^ 1);  // overlaps compute below
    const f16* ab = Asm + sel * CH;
    const f16* bb = Bsm + sel * CH;
    f16x8 af[4][2], bf[4][2];
#pragma unroll
    for (int i = 0; i < 4; ++i)
#pragma unroll
      for (int kk = 0; kk < 2; ++kk) {
        af[i][kk] = *(const f16x8*)&ab[aoffs[i][kk]];
        bf[i][kk] = *(const f16x8*)&bb[boffs[i][kk]];
      }
#pragma unroll
    for (int kk = 0; kk < 2; ++kk)
#pragma unroll
      for (int i = 0; i < 4; ++i)
#pragma unroll
        for (int j = 0; j < 4; ++j)
          acc[i][j] = __builtin_amdgcn_mfma_f32_16x16x32_f16(af[i][kk], bf[j][kk], acc[i][j], 0, 0, 0);
    sel ^= 1;
  }

  const size_t pbase = (size_t)blockIdx.z * NB * Cout * HW;
#pragma unroll
  for (int i = 0; i < 4; ++i) {
    int mg = m0 + wm * 64 + i * 16 + quad * 4;
    int n = mg / HW, p = mg - n * HW;
#pragma unroll
    for (int j = 0; j < 4; ++j) {
      int co = co0 + wn * 64 + j * 16 + lr;
      f32x4 v = acc[i][j];
      f16x4 h;
#pragma unroll
      for (int r = 0; r < 4; ++r) h[r] = (f16)v[r];
      *(f16x4*)&part[pbase + ((size_t)n * Cout + co) * HW + p] = h;
    }
  }
}

// ---------------- reduce S partials + bias (+add)(+lrelu) + GN partials -----
// grids are exact (no early-return) so the barrier is safe.
__global__ __launch_bounds__(256) void reduceS_kernel(
    const f16* __restrict__ part, const float* __restrict__ bias,
    const float* __restrict__ add, float* __restrict__ out,
    int Cout, int HW, int S, int do_lrelu, int total4,
    float* __restrict__ gnp, int G, int Sg) {
  __shared__ float red[512];
  int idx = blockIdx.x * 256 + threadIdx.x;
  if (idx >= total4) return;
  size_t sstride = (size_t)NB * Cout * HW;
  int hw4 = HW >> 2;
  int p4 = idx % hw4; int t = idx / hw4;
  int c = t % Cout;
  size_t eoff = (size_t)t * HW + p4 * 4;
  float b = bias[c];
  f32x4 o = {b, b, b, b};
  for (int s = 0; s < S; ++s) {
    f16x4 a = *(const f16x4*)(part + s * sstride + eoff);
#pragma unroll
    for (int r = 0; r < 4; ++r) o[r] += (float)a[r];
  }
  if (add) {
    f32x4 av = *(const f32x4*)(add + eoff);
#pragma unroll
    for (int r = 0; r < 4; ++r) o[r] += av[r];
  }
  if (do_lrelu)
#pragma unroll
    for (int r = 0; r < 4; ++r) o[r] = o[r] > 0.f ? o[r] : 0.2f * o[r];
  *(f32x4*)(out + eoff) = o;
  if (gnp) {
    float ls = o[0] + o[1] + o[2] + o[3];
    float ls2 = o[0]*o[0] + o[1]*o[1] + o[2]*o[2] + o[3]*o[3];
    red[threadIdx.x] = ls; red[256 + threadIdx.x] = ls2;
    __syncthreads();
    for (int st = 128; st > 0; st >>= 1) {
      if (threadIdx.x < st) {
        red[threadIdx.x] += red[threadIdx.x + st];
        red[256 + threadIdx.x] += red[256 + threadIdx.x + st];
      }
      __syncthreads();
    }
    if (threadIdx.x == 0) {
      int flat0 = blockIdx.x * 1024;
      int chw = Cout * HW;
      int n = flat0 / chw;
      int rem = flat0 - n * chw;
      int L = (Cout / G) * HW;
      int g = rem / L;
      int s = (rem - g * L) >> 10;
      gnp[((n * G + g) * Sg + s) * 2] = red[0];
      gnp[((n * G + g) * Sg + s) * 2 + 1] = red[256];
    }
  }
}

// ---------------- conv_mfma2: 128x64x64 single-buffer (Cout=64) ------------
__global__ __launch_bounds__(256) void conv_mfma2_kernel(
    const f16* __restrict__ A, const f16* __restrict__ Wp,
    const float* __restrict__ bias, float* __restrict__ out,
    int Cin, int H, int W, int Cout, int HW, int do_lrelu) {
  constexpr int BM = 128, BN = 64, BK = 64;
  __shared__ f16 Asm[BM * BK];
  __shared__ f16 Bsm[BN * BK];

  const int tid = threadIdx.x;
  const int w = tid >> 6, lane = tid & 63;
  const int m0 = blockIdx.x * BM;
  const int co0 = blockIdx.y * BN;
  const int Wp2 = W + 2;

  const f16* gA[4];
  int lAoff[4];
#pragma unroll
  for (int e = 0; e < 4; ++e) {
    int c = e * 256 + tid;
    int r = c >> 3, j = c & 7;
    int jx = j ^ (r & 7);
    int m = m0 + r; int n = m / HW; int p = m - n * HW;
    int y = p / W; int x = p - y * W;
    gA[e] = A + (((size_t)n * (H + 2) + y + 1) * Wp2 + (x + 1)) * Cin + jx * 8;
    lAoff[e] = (e * 256 + w * 64) * 8;
  }
  const f16* gB[2];
  int lBoff[2];
#pragma unroll
  for (int e = 0; e < 2; ++e) {
    int c = e * 256 + tid;
    int r = c >> 3, j = c & 7;
    int jx = j ^ (r & 7);
    gB[e] = Wp + (size_t)(co0 + r) * Cin + jx * 8;
    lBoff[e] = (e * 256 + w * 64) * 8;
  }

  const int wm = w & 1, wn = w >> 1;
  const int lr = lane & 15, quad = lane >> 4;
  int aoffs[4][2], boffs[2][2];
#pragma unroll
  for (int i = 0; i < 4; ++i)
#pragma unroll
    for (int kk = 0; kk < 2; ++kk) {
      int r = wm * 64 + i * 16 + lr;
      int cidx = kk * 4 + quad;
      aoffs[i][kk] = (r * 8 + (cidx ^ (r & 7))) * 8;
    }
#pragma unroll
  for (int jn = 0; jn < 2; ++jn)
#pragma unroll
    for (int kk = 0; kk < 2; ++kk) {
      int rb = wn * 32 + jn * 16 + lr;
      int cidx = kk * 4 + quad;
      boffs[jn][kk] = (rb * 8 + (cidx ^ (rb & 7))) * 8;
    }

  f32x4 acc[4][2];
#pragma unroll
  for (int i = 0; i < 4; ++i)
#pragma unroll
    for (int jn = 0; jn < 2; ++jn) acc[i][jn] = (f32x4){0.f, 0.f, 0.f, 0.f};

  for (int tap = 0; tap < 9; ++tap) {
    const int dy = tap / 3 - 1, dx = tap % 3 - 1;
    const long tapA = ((long)dy * Wp2 + dx) * Cin;
    const long tapB = (size_t)tap * Cout * Cin;
    for (int kc = 0; kc < Cin; kc += BK) {
      __syncthreads();
#pragma unroll
      for (int e = 0; e < 4; ++e) LLDS16(gA[e] + tapA + kc, Asm + lAoff[e]);
#pragma unroll
      for (int e = 0; e < 2; ++e) LLDS16(gB[e] + tapB + kc, Bsm + lBoff[e]);
      __syncthreads();

      f16x8 af[4][2], bf[2][2];
#pragma unroll
      for (int i = 0; i < 4; ++i)
#pragma unroll
        for (int kk = 0; kk < 2; ++kk) af[i][kk] = *(const f16x8*)&Asm[aoffs[i][kk]];
#pragma unroll
      for (int jn = 0; jn < 2; ++jn)
#pragma unroll
        for (int kk = 0; kk < 2; ++kk) bf[jn][kk] = *(const f16x8*)&Bsm[boffs[jn][kk]];
#pragma unroll
      for (int kk = 0; kk < 2; ++kk)
#pragma unroll
        for (int i = 0; i < 4; ++i)
#pragma unroll
          for (int jn = 0; jn < 2; ++jn)
            acc[i][jn] = __builtin_amdgcn_mfma_f32_16x16x32_f16(af[i][kk], bf[jn][kk], acc[i][jn], 0, 0, 0);
    }
  }

#pragma unroll
  for (int i = 0; i < 4; ++i) {
    int mg = m0 + wm * 64 + i * 16 + quad * 4;
    int n = mg / HW, p = mg - n * HW;
#pragma unroll
    for (int jn = 0; jn < 2; ++jn) {
      int co = co0 + wn * 32 + jn * 16 + lr;
      float b = bias[co];
      f32x4 v = acc[i][jn];
#pragma unroll
      for (int r = 0; r < 4; ++r) {
        float u = v[r] + b;
        v[r] = (do_lrelu && u < 0.f) ? 0.2f * u : u;
      }
      *(f32x4*)&out[((size_t)n * Cout + co) * HW + p] = v;
    }
  }
}

// ---------------- direct 3x3 conv, CO per thread, optional gn1 partials -----
// When gnp != null: Cout==CO (grid.y==1), 8-ch groups, S = gridDim.x.
template <int CO, int CIC>
__global__ __launch_bounds__(256) void conv3x3_kernel(
    const float* __restrict__ in, const float* __restrict__ wgt,
    const float* __restrict__ bias, float* __restrict__ out,
    int Cin, int H, int W, int Cout, int do_lrelu, float* __restrict__ gnp) {
  __shared__ float sm[CIC][18][18];  // 1296 floats, reused as reduction space
  int tiles_x = W >> 4;
  int bt = blockIdx.x;
  int tx0 = (bt % tiles_x) << 4;
  int ty0 = (bt / tiles_x) << 4;
  int co0 = blockIdx.y * CO;
  int n = blockIdx.z;
  int tid = threadIdx.x;
  int lx = tid & 15, ly = tid >> 4;

  float acc[CO];
#pragma unroll
  for (int i = 0; i < CO; i++) acc[i] = 0.f;

  const float* inb = in + (size_t)n * Cin * H * W;

  for (int ci0 = 0; ci0 < Cin; ci0 += CIC) {
    __syncthreads();
    for (int idx = tid; idx < CIC * 324; idx += 256) {
      int ci = idx / 324;
      int r = idx - ci * 324;
      int gy = r / 18, gx = r - gy * 18;
      int iy = ty0 + gy - 1, ix = tx0 + gx - 1;
      float v = 0.f;
      if ((unsigned)iy < (unsigned)H && (unsigned)ix < (unsigned)W)
        v = inb[((size_t)(ci0 + ci)) * H * W + (size_t)iy * W + ix];
      sm[ci][gy][gx] = v;
    }
    __syncthreads();
#pragma unroll
    for (int ci = 0; ci < CIC; ci++) {
      float x00 = sm[ci][ly][lx],     x01 = sm[ci][ly][lx + 1],     x02 = sm[ci][ly][lx + 2];
      float x10 = sm[ci][ly + 1][lx], x11 = sm[ci][ly + 1][lx + 1], x12 = sm[ci][ly + 1][lx + 2];
      float x20 = sm[ci][ly + 2][lx], x21 = sm[ci][ly + 2][lx + 1], x22 = sm[ci][ly + 2][lx + 2];
      const float* wp = wgt + ((size_t)co0 * Cin + (ci0 + ci)) * 9;
#pragma unroll
      for (int co = 0; co < CO; co++) {
        const float* wc = wp + (size_t)co * Cin * 9;
        float a = acc[co];
        a = fmaf(wc[0], x00, a); a = fmaf(wc[1], x01, a); a = fmaf(wc[2], x02, a);
        a = fmaf(wc[3], x10, a); a = fmaf(wc[4], x11, a); a = fmaf(wc[5], x12, a);
        a = fmaf(wc[6], x20, a); a = fmaf(wc[7], x21, a); a = fmaf(wc[8], x22, a);
        acc[co] = a;
      }
    }
  }

  float vout[CO];
#pragma unroll
  for (int co = 0; co < CO; co++) {
    float v = acc[co] + bias[co0 + co];
    if (do_lrelu) v = v > 0.f ? v : 0.2f * v;
    vout[co] = v;
  }

  if (gnp) {  // gn1 partials: 2 groups of 8 channels
    float p0 = 0.f, q0 = 0.f, p1 = 0.f, q1 = 0.f;
#pragma unroll
    for (int co = 0; co < 8; ++co) { p0 += vout[co]; q0 += vout[co] * vout[co]; }
#pragma unroll
    for (int co = 8; co < CO; ++co) { p1 += vout[co]; q1 += vout[co] * vout[co]; }
    float* red = &sm[0][0][0];
    __syncthreads();
    red[tid] = p0; red[256 + tid] = q0; red[512 + tid] = p1; red[768 + tid] = q1;
    __syncthreads();
    for (int st = 128; st > 0; st >>= 1) {
      if (tid < st) {
        red[tid] += red[tid + st]; red[256 + tid] += red[256 + tid + st];
        red[512 + tid] += red[512 + tid + st]; red[768 + tid] += red[768 + tid + st];
      }
      __syncthreads();
    }
    if (tid == 0) {
      int S = gridDim.x;
      gnp[((n * 2 + 0) * S + blockIdx.x) * 2]     = red[0];
      gnp[((n * 2 + 0) * S + blockIdx.x) * 2 + 1] = red[256];
      gnp[((n * 2 + 1) * S + blockIdx.x) * 2]     = red[512];
      gnp[((n * 2 + 1) * S + blockIdx.x) * 2 + 1] = red[768];
    }
  }

  int oy = ty0 + ly, ox = tx0 + lx;
#pragma unroll
  for (int co = 0; co < CO; co++)
    out[(((size_t)n * Cout + co0 + co) * H + oy) * W + ox] = vout[co];
}

// ---------------- group norm: stats (partials) / apply (partial-based) ------
__global__ __launch_bounds__(256) void gn_stats_kernel(const float* __restrict__ x,
                                                       float* __restrict__ part,
                                                       int C, int HW, int G, int SPLIT) {
  __shared__ float red[512];
  int gs = blockIdx.x;
  int g = gs / SPLIT, s = gs - g * SPLIT;
  int n = blockIdx.y;
  int cpg = C / G;
  int len = cpg * HW;
  int chunk = len / SPLIT;
  size_t base = ((size_t)n * C + (size_t)g * cpg) * HW + (size_t)s * chunk;
  const f32x4* xp = (const f32x4*)(x + base);
  int chunk4 = chunk >> 2;
  float sm = 0.f, s2 = 0.f;
  for (int i = threadIdx.x; i < chunk4; i += 256) {
    f32x4 v = xp[i];
    sm += v.x + v.y + v.z + v.w;
    s2 += v.x * v.x + v.y * v.y + v.z * v.z + v.w * v.w;
  }
  red[threadIdx.x] = sm; red[256 + threadIdx.x] = s2;
  __syncthreads();
  for (int st = 128; st > 0; st >>= 1) {
    if (threadIdx.x < st) {
      red[threadIdx.x] += red[threadIdx.x + st];
      red[256 + threadIdx.x] += red[256 + threadIdx.x + st];
    }
    __syncthreads();
  }
  if (threadIdx.x == 0) {
    int o = ((n * G + g) * SPLIT + s) * 2;
    part[o] = red[0]; part[o + 1] = red[256];
  }
}

// apply, mean/inv computed from Sg partials (block-uniform group)
__global__ __launch_bounds__(256) void gn_apply_kernel(float* __restrict__ x,
                                                       const float* __restrict__ gnp,
                                                       const float* __restrict__ gamma,
                                                       const float* __restrict__ beta,
                                                       int C, int HW, int G, int Sg, int len,
                                                       int total4) {
  int idx = blockIdx.x * 256 + threadIdx.x;
  if (idx >= total4) return;
  int flat0 = blockIdx.x * 1024;
  int chw = C * HW;
  int n = flat0 / chw;
  int rem = flat0 - n * chw;
  int L = (C / G) * HW;
  int g = rem / L;
  const float* pp = gnp + (size_t)((n * G + g) * Sg) * 2;
  float s = 0.f, s2 = 0.f;
  for (int i = 0; i < Sg; ++i) { s += pp[2 * i]; s2 += pp[2 * i + 1]; }
  float mean = s / (float)len;
  float var = s2 / (float)len - mean * mean;
  if (var < 0.f) var = 0.f;
  float inv = rsqrtf(var + 1e-5f);
  int hw4 = HW >> 2;
  int p4 = idx % hw4; int t = idx / hw4;
  int c = t % C;
  float ga = gamma[c], be = beta[c];
  f32x4* xp = (f32x4*)(x + ((size_t)t * HW)) + p4;
  f32x4 v = *xp;
#pragma unroll
  for (int r = 0; r < 4; ++r) v[r] = (v[r] - mean) * inv * ga + be;
  *xp = v;
}

// ---------------------------------------------------------------------------

extern "C" void kernel_launch(void* const* d_in, const int* in_sizes, int n_in,
                              void* d_out, int out_size, void* d_ws, size_t ws_size,
                              hipStream_t stream) {
  const float* x        = (const float*)d_in[0];
  const float* conv1_w  = (const float*)d_in[1];
  const float* conv1_b  = (const float*)d_in[2];
  const float* conv2_w  = (const float*)d_in[3];
  const float* conv2_b  = (const float*)d_in[4];
  const float* conv3_w  = (const float*)d_in[5];
  const float* conv3_b  = (const float*)d_in[6];
  const float* conv4_w  = (const float*)d_in[7];
  const float* conv4_b  = (const float*)d_in[8];
  const float* convd1_w = (const float*)d_in[9];
  const float* convd1_b = (const float*)d_in[10];
  const float* convd2_w = (const float*)d_in[11];
  const float* convd2_b = (const float*)d_in[12];
  const float* convd3_w = (const float*)d_in[13];
  const float* convd3_b = (const float*)d_in[14];
  const float* convd4_w = (const float*)d_in[15];
  const float* convd4_b = (const float*)d_in[16];
  const float* final_w  = (const float*)d_in[17];
  const float* gn1_w = (const float*)d_in[18];
  const float* gn1_b = (const float*)d_in[19];
  const float* gn2_w = (const float*)d_in[20];
  const float* gn2_b = (const float*)d_in[21];
  const float* gn3_w = (const float*)d_in[22];
  const float* gn3_b = (const float*)d_in[23];
  const float* gn4_w = (const float*)d_in[24];
  const float* gn4_b = (const float*)d_in[25];

  char* base = (char*)d_ws;
  size_t off = 0;
  auto allocB = [&](size_t bytes) { size_t o = off; off = (off + bytes + 255) & ~(size_t)255; return o; };

  size_t o_sw1  = allocB(16 * 108 * 4);
  size_t o_swd1 = allocB(12 * 144 * 4);
  size_t o_swd2 = allocB(16 * 288 * 4);
  size_t o_swf  = allocB(6 * 4);
  size_t o_pw2  = allocB((size_t)9 * 64 * 64 * 2);
  size_t o_pw3  = allocB((size_t)9 * 256 * 256 * 2);
  size_t o_pw4  = allocB((size_t)9 * 1024 * 1024 * 2);
  size_t o_pwd3 = allocB((size_t)9 * 64 * 128 * 2);
  size_t o_pwd4 = allocB((size_t)9 * 256 * 512 * 2);
  size_t o_R1   = allocB((size_t)NB * 66 * 66 * 128 * 2);  // part | ah64 | ah128
  size_t o_R2   = allocB((size_t)NB * 34 * 34 * 512 * 2);  // ah256 | ah1k | ah512
  size_t o_gnp  = allocB(16384 * 4);                        // gn block partials
  size_t o_c1 = allocB((size_t)NB * 16 * 128 * 128 * 4);
  size_t o_c2 = allocB((size_t)NB * 64 * 64 * 64 * 4);
  size_t o_c3 = allocB((size_t)NB * 256 * 32 * 32 * 4);
  size_t o_w4 = allocB((size_t)NB * 1024 * 16 * 16 * 4);
  size_t o_t1 = allocB((size_t)NB * 1024 * 16 * 16 * 4);
  size_t o_t2 = allocB((size_t)NB * 512 * 32 * 32 * 4);

  if (off > ws_size) return;

  float* c1 = (float*)(base + o_c1);
  float* c2 = (float*)(base + o_c2);
  float* c3 = (float*)(base + o_c3);
  float* w4 = (float*)(base + o_w4);
  float* t1 = (float*)(base + o_t1);
  float* t2 = (float*)(base + o_t2);
  f16* part  = (f16*)(base + o_R1);
  f16* ah64  = (f16*)(base + o_R1);
  f16* ah128 = (f16*)(base + o_R1);
  f16* ah256 = (f16*)(base + o_R2);
  f16* ah1k  = (f16*)(base + o_R2);
  f16* ah512 = (f16*)(base + o_R2);
  f16* pw2 = (f16*)(base + o_pw2);
  f16* pw3 = (f16*)(base + o_pw3);
  f16* pw4 = (f16*)(base + o_pw4);
  f16* pwd3 = (f16*)(base + o_pwd3);
  f16* pwd4 = (f16*)(base + o_pwd4);
  float* gnp = (float*)(base + o_gnp);

  // ---- upfront ----
  {
    int n0 = NB * (2 * 66 + 2 * 64) * (64 / 8);
    int n1 = NB * (2 * 34 + 2 * 32) * (256 / 8);
    int tot = n0 + n1;
    halo2_kernel<<<(tot + 255) / 256, 256, 0, stream>>>(ah64, 64, 64, 64, n0,
                                                        ah256, 256, 32, 32, tot);
  }
  ws_all_kernel<<<46, 256, 0, stream>>>(conv1_w, (float*)(base + o_sw1),
                                        convd1_w, (float*)(base + o_swd1),
                                        convd2_w, (float*)(base + o_swd2),
                                        final_w, (float*)(base + o_swf));
  ws_f16_all_kernel<<<1664, 256, 0, stream>>>(conv2_w, pw2, conv3_w, pw3, conv4_w, pw4,
                                              convd3_w, pwd3, convd4_w, pwd4);

  auto prep_nhwc = [&](const float* in, f16* ah, int C, int H, int W, int zero) {
    if (zero) {
      int total8 = NB * (2 * (W + 2) + 2 * H) * (C / 8);
      zero_halo_kernel<<<(total8 + 255) / 256, 256, 0, stream>>>(ah, C, H, W, total8);
    }
    dim3 g((H * W) / 256, C / 32, NB);
    to_nhwc_pad_kernel<<<g, 256, 0, stream>>>(in, ah, C, H, W);
  };
  auto cm6 = [&](const f16* a, const f16* wt, const float* b, float* dest, const float* add,
                 int Cin, int Hs, int Ws, int Cout, int lr, int G, int Sg) {
    dim3 g((NB * Hs * Ws) / 128, Cout / 128, 2);
    conv_mfma6_kernel<<<g, 256, 0, stream>>>(a, wt, part, Cin, Hs, Ws, Cout, Hs * Ws);
    int total4 = (NB * Cout * Hs * Ws) >> 2;
    reduceS_kernel<<<(total4 + 255) / 256, 256, 0, stream>>>(
        part, b, add, dest, Cout, Hs * Ws, 2, lr, total4, G ? gnp : nullptr, G, Sg);
  };
  auto cm2 = [&](const f16* a, const f16* wt, const float* b, float* o,
                 int Cin, int Hs, int Ws, int Cout, int lr) {
    dim3 g((NB * Hs * Ws) / 128, Cout / 64);
    conv_mfma2_kernel<<<g, 256, 0, stream>>>(a, wt, b, o, Cin, Hs, Ws, Cout, Hs * Ws, lr);
  };
  auto launch_wt = [&](const float* in, float* out, int C, int Ho, int Wo) {
    int total = NB * C * Ho * Wo;
    wt_kernel<<<(total + 255) / 256, 256, 0, stream>>>(in, out, C, Ho, Wo, total);
  };
  auto apply = [&](float* xb, const float* g, const float* b, int C, int HW, int G, int Sg) {
    int len = (C / G) * HW;
    int total4 = (NB * C * HW) >> 2;
    gn_apply_kernel<<<(total4 + 255) / 256, 256, 0, stream>>>(xb, gnp, g, b, C, HW, G, Sg,
                                                              len, total4);
  };
  auto stats = [&](const float* xb, int C, int HW, int G, int SPLIT) {
    dim3 gsd(G * SPLIT, NB);
    gn_stats_kernel<<<gsd, 256, 0, stream>>>(xb, gnp, C, HW, G, SPLIT);
  };
  auto concat_iwt = [&](const float* skip, const float* v, float* out, int C, int Hh, int Wh,
                        const float* gg, const float* gb, int G, int Sg) {
    int totalA = NB * C * 4 * Hh * Wh;
    int total = totalA + NB * C * Hh * Wh;
    int len = G ? ((4 * C) / G) * Hh * Wh : 1;
    concat_iwt_kernel<<<(total + 255) / 256, 256, 0, stream>>>(
        skip, v, out, G ? gnp : nullptr, gg, gb, G, Sg, len, C, Hh, Wh, totalA, total);
  };

  // ==== encoder ====
  launch_wt(x, t1, 3, 128, 128);                                    // w1 -> t1
  {
    dim3 g(64, 1, NB);
    conv3x3_kernel<16, 4><<<g, 256, 0, stream>>>(t1, (float*)(base + o_sw1), conv1_b,
                                                 c1, 12, 128, 128, 16, 1, gnp);
  }
  apply(c1, gn1_w, gn1_b, 16, 128 * 128, 2, 64);                    // gn1

  launch_wt(c1, t1, 16, 64, 64);                                    // w2 -> t1
  prep_nhwc(t1, ah64, 64, 64, 64, 0);
  cm2(ah64, pw2, conv2_b, c2, 64, 64, 64, 64, 1);                   // c2
  stats(c2, 64, 4096, 8, 16);
  apply(c2, gn2_w, gn2_b, 64, 4096, 8, 16);

  launch_wt(c2, t1, 64, 32, 32);                                    // w3 -> t1
  prep_nhwc(t1, ah256, 256, 32, 32, 0);
  cm6(ah256, pw3, conv3_b, c3, nullptr, 256, 32, 32, 256, 1, 32, 8);  // c3 (+partials)
  apply(c3, gn3_w, gn3_b, 256, 1024, 32, 8);

  launch_wt(c3, w4, 256, 16, 16);                                   // w4 (fp32 residual)
  prep_nhwc(w4, ah1k, 1024, 16, 16, 1);

  cm6(ah1k, pw4, conv4_b, t1, nullptr, 1024, 16, 16, 1024, 1, 128, 2);  // c4 -> t1
  {
    dim3 g(1, 32, NB);
    gn_nhwc_kernel<<<g, 256, 0, stream>>>(t1, gnp, gn4_w, gn4_b, ah1k, 1024, 16, 16,
                                          128, 2, 2048);
  }
  cm6(ah1k, pw4, conv4_b, t2, nullptr, 1024, 16, 16, 1024, 1, 128, 2);  // c5 -> t2
  {
    dim3 g(1, 32, NB);
    gn_nhwc_kernel<<<g, 256, 0, stream>>>(t2, gnp, gn4_w, gn4_b, ah1k, 1024, 16, 16,
                                          128, 2, 2048);
  }
  cm6(ah1k, pw4, conv4_b, t1, w4, 1024, 16, 16, 1024, 1, 0, 0);     // ic4 = lrelu(c6+w4)

  // ==== decoder ====
  concat_iwt(c3, t1, t2, 256, 16, 16, nullptr, nullptr, 0, 0);      // iw4 -> t2 (no GN)
  prep_nhwc(t2, ah512, 512, 32, 32, 1);
  cm6(ah512, pwd4, convd4_b, t1, nullptr, 512, 32, 32, 256, 1, 32, 8);  // ic3 (+partials)
  concat_iwt(c2, t1, t2, 64, 32, 32, gn3_w, gn3_b, 32, 8);          // iw3 -> t2 (gn3 inline)
  prep_nhwc(t2, ah128, 128, 64, 64, 1);
  cm2(ah128, pwd3, convd3_b, t1, 128, 64, 64, 64, 1);               // ic2 -> t1
  stats(t1, 64, 4096, 8, 16);
  concat_iwt(c1, t1, t2, 16, 64, 64, gn2_w, gn2_b, 8, 16);          // iw2 -> t2 (gn2 inline)
  {
    dim3 g(64, 1, NB);
    conv3x3_kernel<16, 4><<<g, 256, 0, stream>>>(t2, (float*)(base + o_swd2), convd2_b,
                                                 t1, 32, 128, 128, 16, 1, gnp);
  }
  apply(t1, gn1_w, gn1_b, 16, 128 * 128, 2, 64);                    // gn1 on ic1
  {
    dim3 g(64, 1, NB);
    conv3x3_kernel<12, 4><<<g, 256, 0, stream>>>(t1, (float*)(base + o_swd1), convd1_b,
                                                 t2, 16, 128, 128, 12, 1, nullptr);
  }
  {
    int total = NB * 128 * 128;
    iwt_final_kernel<<<(total + 255) / 256, 256, 0, stream>>>(t2, (float*)(base + o_swf),
                                                              (float*)d_out, total);
  }
}